// Round 13
// baseline (1022.742 us; speedup 1.0000x reference)
//
#include <hip/hip_runtime.h>
#include <hip/hip_bf16.h>
#include <math.h>

#define N_NODES 50000
#define N_EDGES 400000
#define N_GRAPHS 2500
#define D 128
#define D3 384
#define N_RBF 20
#define R_CUT 5.0f
#define PI_F 3.14159265358979f
#define GEB 16   // gate edge batch (one MFMA row-block)
#define GLDS_STRIDE 388  // 776 B row stride: mult of 8 for b64 writes

typedef __attribute__((ext_vector_type(8))) short bf16x8;
typedef __attribute__((ext_vector_type(4))) short short4v;
typedef __attribute__((ext_vector_type(4))) float f32x4;

__device__ __forceinline__ float silu_f(float x) {
    return x / (1.0f + __expf(-x));
}
__device__ __forceinline__ short f2bf(float x) {
    union { float f; unsigned u; } v; v.f = x;
    unsigned r = (v.u + 0x7FFFu + ((v.u >> 16) & 1u)) >> 16;
    return (short)r;
}
__device__ __forceinline__ float bf2f(short x) {
    union { unsigned u; float f; } v; v.u = ((unsigned)(unsigned short)x) << 16;
    return v.f;
}
__device__ __forceinline__ float bflo(unsigned u) {
    union { unsigned x; float f; } v; v.x = u << 16; return v.f;
}
__device__ __forceinline__ float bfhi(unsigned u) {
    union { unsigned x; float f; } v; v.x = u & 0xFFFF0000u; return v.f;
}
__device__ __forceinline__ unsigned packbf(float a, float b) {
    return ((unsigned)(unsigned short)f2bf(a)) | (((unsigned)(unsigned short)f2bf(b)) << 16);
}

// ---------------- all weight packs in ONE dispatch ----------------
#define MAXJOBS 19
struct PackJobs {
    const float* W[MAXJOBS];
    short* P[MAXJOBS];
    int K[MAXJOBS];
    int N[MAXJOBS];
    int boff[MAXJOBS + 1];
    int njobs;
};
__global__ void k_packall(PackJobs jobs) {
    int b = blockIdx.x;
    int j = 0;
    while (j + 1 < jobs.njobs && b >= jobs.boff[j + 1]) ++j;
    int t = (b - jobs.boff[j]) * 256 + threadIdx.x;
    int K = jobs.K[j], N = jobs.N[j];
    int NKT = K / 32;
    int total = (N / 16) * NKT * 64;
    if (t >= total) return;
    const float* W = jobs.W[j];
    short* P = jobs.P[j];
    int lane = t & 63;
    int kt = (t >> 6) % NKT;
    int nt = (t >> 6) / NKT;
    int k0 = kt * 32 + (lane >> 4) * 8;
    int col = nt * 16 + (lane & 15);
    #pragma unroll
    for (int q = 0; q < 8; ++q)
        P[(size_t)t * 8 + q] = f2bf(W[(size_t)(k0 + q) * N + col]);
}

// pack [rbf_w(20 rows); rbf_b(1 row); zeros] -> frags, 3 blocks in one dispatch
__global__ void k_packrbf(const float* __restrict__ rbf_w, const float* __restrict__ rbf_b,
                          short* __restrict__ P) {
    int t = blockIdx.x * 256 + threadIdx.x;
    if (t >= 3 * 1536) return;
    int i = t / 1536;
    int r = t - i * 1536;        // nt*64 + lane
    int lane = r & 63;
    int nt = r >> 6;
    int col = nt * 16 + (lane & 15);
    int k0 = (lane >> 4) * 8;
    const float* W = rbf_w + (size_t)i * N_RBF * D3;
    const float* B = rbf_b + (size_t)i * D3;
    short* out = P + (size_t)i * 12288 + (size_t)r * 8;
    #pragma unroll
    for (int q = 0; q < 8; ++q) {
        int k = k0 + q;
        float v = (k < N_RBF) ? W[(size_t)k * D3 + col] : ((k == N_RBF) ? B[col] : 0.0f);
        out[q] = f2bf(v);
    }
}

// ---------------- fused two-layer MLP: Cout = silu(A@W1+b1)@W2+b2 ----------------
// stage1: Kx128 GEMM + silu -> wave-private LDS tile; stage2: swapped-operand 128x384 GEMM
// (lane holds 4 consecutive output channels of one node -> b64 coalesced stores).
// AMODE1: 1 = A f32 ; 2 = A1 bf16 (k<128) + A2 f32 (k>=128)
template<int K1, int AMODE1>
__global__ __launch_bounds__(256) void k_mlp2(const void* __restrict__ Aptr,
                                              const void* __restrict__ A2ptr,
                                              const short* __restrict__ Bp1,
                                              const float* __restrict__ b1,
                                              const short* __restrict__ Bp2,
                                              const float* __restrict__ b2,
                                              short* __restrict__ Cout, int M) {
    constexpr int NKT1 = K1 / 32;
    __shared__ __align__(16) short h_lds[4][32][136];  // 34.8 KB, stride 272 B
    int lane = threadIdx.x & 63, wv = threadIdx.x >> 6;
    int tile = blockIdx.x * 4 + wv;
    int base = tile * 32;
    if (base >= M) return;
    bool has2 = (base + 16 < M);
    int r16 = lane & 15;
    int kgrp = (lane >> 4) * 8;
    int arow0 = base + r16;
    int arow1 = has2 ? (base + 16 + r16) : arow0;

    bf16x8 a0[NKT1], a1[NKT1];
    #pragma unroll
    for (int ss = 0; ss < 2; ++ss) {
        int arow = ss ? arow1 : arow0;
        bf16x8* a = ss ? a1 : a0;
        if (AMODE1 == 1) {
            const float* A = (const float*)Aptr + (size_t)arow * K1 + kgrp;
            #pragma unroll
            for (int kt = 0; kt < NKT1; ++kt)
                #pragma unroll
                for (int j = 0; j < 8; ++j) a[kt][j] = f2bf(A[kt * 32 + j]);
        } else {
            const short* A1 = (const short*)Aptr + (size_t)arow * 128 + kgrp;
            const float* A2 = (const float*)A2ptr + (size_t)arow * 128 + kgrp;
            #pragma unroll
            for (int kt = 0; kt < 4 && kt < NKT1; ++kt) a[kt] = *(const bf16x8*)(A1 + kt * 32);
            #pragma unroll
            for (int kt = 4; kt < NKT1; ++kt)
                #pragma unroll
                for (int j = 0; j < 8; ++j) a[kt][j] = f2bf(A2[(kt - 4) * 32 + j]);
        }
    }

    int rloc = (lane >> 4) * 4;
    int ccol = lane & 15;
    const bf16x8* Bv1 = (const bf16x8*)Bp1;
    #pragma unroll
    for (int nt = 0; nt < 8; ++nt) {
        f32x4 acc0 = {0.f, 0.f, 0.f, 0.f};
        f32x4 acc1 = {0.f, 0.f, 0.f, 0.f};
        #pragma unroll
        for (int kt = 0; kt < NKT1; ++kt) {
            bf16x8 b = Bv1[(nt * NKT1 + kt) * 64 + lane];
            acc0 = __builtin_amdgcn_mfma_f32_16x16x32_bf16(a0[kt], b, acc0, 0, 0, 0);
            acc1 = __builtin_amdgcn_mfma_f32_16x16x32_bf16(a1[kt], b, acc1, 0, 0, 0);
        }
        int col = nt * 16 + ccol;
        float bs = b1[col];
        #pragma unroll
        for (int j = 0; j < 4; ++j) {
            h_lds[wv][rloc + j][col]      = f2bf(silu_f(acc0[j] + bs));
            h_lds[wv][16 + rloc + j][col] = f2bf(silu_f(acc1[j] + bs));
        }
    }
    // wave-local LDS: compiler inserts lgkmcnt waits; no barrier needed.
    bf16x8 ha0[4], ha1[4];
    #pragma unroll
    for (int kt = 0; kt < 4; ++kt) {
        ha0[kt] = *(const bf16x8*)&h_lds[wv][r16][kt * 32 + kgrp];
        ha1[kt] = *(const bf16x8*)&h_lds[wv][16 + r16][kt * 32 + kgrp];
    }
    // stage 2, swapped operands: D[ch][node]; lane = node (lane&15), 4 consecutive ch.
    const bf16x8* Bv2 = (const bf16x8*)Bp2;
    int chb = rloc;   // channel base within tile
    #pragma unroll
    for (int nt = 0; nt < 24; ++nt) {
        f32x4 acc0 = {0.f, 0.f, 0.f, 0.f};
        f32x4 acc1 = {0.f, 0.f, 0.f, 0.f};
        #pragma unroll
        for (int kt = 0; kt < 4; ++kt) {
            bf16x8 b = Bv2[(nt * 4 + kt) * 64 + lane];
            acc0 = __builtin_amdgcn_mfma_f32_16x16x32_bf16(b, ha0[kt], acc0, 0, 0, 0);
            acc1 = __builtin_amdgcn_mfma_f32_16x16x32_bf16(b, ha1[kt], acc1, 0, 0, 0);
        }
        int ch = nt * 16 + chb;
        short4v w0, w1;
        #pragma unroll
        for (int j = 0; j < 4; ++j) {
            w0[j] = f2bf(acc0[j] + b2[ch + j]);
            w1[j] = f2bf(acc1[j] + b2[ch + j]);
        }
        *(short4v*)&Cout[(size_t)(base + r16) * D3 + ch] = w0;
        if (has2)
            *(short4v*)&Cout[(size_t)(base + 16 + r16) * D3 + ch] = w1;
    }
}

// ---------------- fused U/V GEMM, swapped-operand epilogue (b64 coalesced stores) ----------------
__global__ __launch_bounds__(256) void k_gemmUV(const short* __restrict__ A,
                                                const short* __restrict__ Bp,
                                                short* __restrict__ Cu,
                                                short* __restrict__ Cv, int M) {
    int lane = threadIdx.x & 63, wv = threadIdx.x >> 6;
    int tile = blockIdx.x * 4 + wv;
    int base = tile * 32;
    if (base >= M) return;
    bool has2 = (base + 16 < M);
    int r16 = lane & 15;
    int kgrp = (lane >> 4) * 8;
    const short* Ar0 = A + (size_t)(base + r16) * 128 + kgrp;
    const short* Ar1 = A + (size_t)((has2 ? base + 16 : base) + r16) * 128 + kgrp;
    bf16x8 a0[4], a1[4];
    #pragma unroll
    for (int kt = 0; kt < 4; ++kt) {
        a0[kt] = *(const bf16x8*)(Ar0 + kt * 32);
        a1[kt] = *(const bf16x8*)(Ar1 + kt * 32);
    }
    int chb = (lane >> 4) * 4;
    const bf16x8* Bv = (const bf16x8*)Bp;
    #pragma unroll
    for (int nt = 0; nt < 16; ++nt) {
        f32x4 acc0 = {0.f, 0.f, 0.f, 0.f};
        f32x4 acc1 = {0.f, 0.f, 0.f, 0.f};
        #pragma unroll
        for (int kt = 0; kt < 4; ++kt) {
            bf16x8 b = Bv[(nt * 4 + kt) * 64 + lane];
            acc0 = __builtin_amdgcn_mfma_f32_16x16x32_bf16(b, a0[kt], acc0, 0, 0, 0);
            acc1 = __builtin_amdgcn_mfma_f32_16x16x32_bf16(b, a1[kt], acc1, 0, 0, 0);
        }
        int ch = nt * 16 + chb;
        short* C = (ch < 128) ? Cu : Cv;   // tiles 0-7 -> U, 8-15 -> V (no straddle)
        int cc = ch & 127;
        short4v w0, w1;
        #pragma unroll
        for (int j = 0; j < 4; ++j) {
            w0[j] = f2bf(acc0[j]);
            w1[j] = f2bf(acc1[j]);
        }
        *(short4v*)&C[(size_t)(base + r16) * 128 + cc] = w0;
        if (has2)
            *(short4v*)&C[(size_t)(base + 16 + r16) * 128 + cc] = w1;
    }
}

// ---------------- fused readout: h = silu(s@W1+b1); out[g] += dot(h, w2) + b2 ----------------
__global__ __launch_bounds__(256) void k_bluefused(const float* __restrict__ s,
                                                   const short* __restrict__ Bp,
                                                   const float* __restrict__ b1,
                                                   const float* __restrict__ w2,
                                                   const float* __restrict__ b2,
                                                   const int* __restrict__ graph_idx,
                                                   float* __restrict__ out, int M) {
    int lane = threadIdx.x & 63, wv = threadIdx.x >> 6;
    int tile = blockIdx.x * 4 + wv;
    int base = tile * 32;
    if (base >= M) return;
    bool has2 = (base + 16 < M);
    int r16 = lane & 15;
    int kgrp = (lane >> 4) * 8;
    int arow0 = base + r16;
    int arow1 = has2 ? (base + 16 + r16) : arow0;
    bf16x8 a0[4], a1[4];
    {
        const float* A = s + (size_t)arow0 * 128 + kgrp;
        #pragma unroll
        for (int kt = 0; kt < 4; ++kt)
            #pragma unroll
            for (int j = 0; j < 8; ++j) a0[kt][j] = f2bf(A[kt * 32 + j]);
        const float* B = s + (size_t)arow1 * 128 + kgrp;
        #pragma unroll
        for (int kt = 0; kt < 4; ++kt)
            #pragma unroll
            for (int j = 0; j < 8; ++j) a1[kt][j] = f2bf(B[kt * 32 + j]);
    }
    int crow0 = base + (lane >> 4) * 4;
    int ccol = lane & 15;
    const bf16x8* Bv = (const bf16x8*)Bp;
    float dot0[4] = {0.f, 0.f, 0.f, 0.f};
    float dot1[4] = {0.f, 0.f, 0.f, 0.f};
    #pragma unroll
    for (int nt = 0; nt < 8; ++nt) {
        f32x4 acc0 = {0.f, 0.f, 0.f, 0.f};
        f32x4 acc1 = {0.f, 0.f, 0.f, 0.f};
        #pragma unroll
        for (int kt = 0; kt < 4; ++kt) {
            bf16x8 b = Bv[(nt * 4 + kt) * 64 + lane];
            acc0 = __builtin_amdgcn_mfma_f32_16x16x32_bf16(a0[kt], b, acc0, 0, 0, 0);
            acc1 = __builtin_amdgcn_mfma_f32_16x16x32_bf16(a1[kt], b, acc1, 0, 0, 0);
        }
        int col = nt * 16 + ccol;
        float bs = b1[col], w = w2[col];
        #pragma unroll
        for (int j = 0; j < 4; ++j) {
            dot0[j] += silu_f(acc0[j] + bs) * w;
            dot1[j] += silu_f(acc1[j] + bs) * w;
        }
    }
    #pragma unroll
    for (int m = 1; m <= 8; m <<= 1) {
        #pragma unroll
        for (int j = 0; j < 4; ++j) {
            dot0[j] += __shfl_xor(dot0[j], m, 64);
            dot1[j] += __shfl_xor(dot1[j], m, 64);
        }
    }
    if (ccol == 0) {
        #pragma unroll
        for (int j = 0; j < 4; ++j) {
            int n = crow0 + j;
            atomicAdd(&out[graph_idx[n]], dot0[j] + b2[0]);
        }
        if (has2) {
            #pragma unroll
            for (int j = 0; j < 4; ++j) {
                int n = crow0 + 16 + j;
                atomicAdd(&out[graph_idx[n]], dot1[j] + b2[0]);
            }
        }
    }
}

// ---------------- embed ----------------
__global__ void k_embed(const int* __restrict__ z, const float* __restrict__ emb,
                        float* __restrict__ s) {
    int i = blockIdx.x * blockDim.x + threadIdx.x;
    if (i < N_NODES * D) {
        int n = i >> 7, c = i & 127;
        s[i] = emb[z[n] * D + c];
    }
}

// ---------------- edge-sort precompute ----------------
__global__ void k_hist(const int* __restrict__ edges, int* __restrict__ cnt) {
    int e = blockIdx.x * 256 + threadIdx.x;
    if (e < N_EDGES) atomicAdd(&cnt[edges[2 * e]], 1);
}

// single-dispatch scan: cnt -> rowptr (exclusive), reset cnt for cursor use
#define SCH 49   // ceil(50000/1024)
__global__ __launch_bounds__(1024) void k_scanall(int* __restrict__ cnt,
                                                  int* __restrict__ rowptr) {
    __shared__ int part[1024];
    int t = threadIdx.x;
    int lo = t * SCH;
    int hi = lo + SCH; if (hi > N_NODES) hi = N_NODES;
    int sum = 0;
    for (int i = lo; i < hi; ++i) sum += cnt[i];
    part[t] = sum;
    __syncthreads();
    for (int off = 1; off < 1024; off <<= 1) {
        int v = (t >= off) ? part[t - off] : 0;
        __syncthreads();
        part[t] += v;
        __syncthreads();
    }
    int run = part[t] - sum;   // exclusive prefix
    for (int i = lo; i < hi; ++i) {
        rowptr[i] = run;
        run += cnt[i];
        cnt[i] = 0;            // reset for cursor phase
    }
    if (t == 1023) rowptr[N_NODES] = N_EDGES;
}

// scatter edges into dst-sorted order; per edge: erbf[32] bf16 (rbf*fc, fc, 0...), rhat float4
__global__ void k_scatter(const int* __restrict__ edges, const float* __restrict__ r_ij,
                          const float* __restrict__ rhat, const int* __restrict__ rowptr,
                          int* __restrict__ cursor, int* __restrict__ esrc,
                          short* __restrict__ erbf, float4* __restrict__ erhat) {
    int e = blockIdx.x * 256 + threadIdx.x;
    if (e >= N_EDGES) return;
    int dst = edges[2 * e], src = edges[2 * e + 1];
    int p = rowptr[dst] + atomicAdd(&cursor[dst], 1);
    esrc[p] = src;
    float r = r_ij[e];
    float fc = (r <= R_CUT) ? 0.5f * (cosf(PI_F * r / R_CUT) + 1.0f) : 0.0f;
    float inv_r = 1.0f / r;
    short rec[32];
    #pragma unroll
    for (int k = 0; k < N_RBF; ++k)
        rec[k] = f2bf(sinf((float)(k + 1) * (PI_F / R_CUT) * r) * inv_r * fc);
    rec[20] = f2bf(fc);
    #pragma unroll
    for (int k = 21; k < 32; ++k) rec[k] = 0;
    short* out = erbf + (size_t)p * 32;
    #pragma unroll
    for (int k = 0; k < 32; ++k) out[k] = rec[k];
    float4 rh;
    rh.x = rhat[3 * e]; rh.y = rhat[3 * e + 1]; rh.z = rhat[3 * e + 2]; rh.w = 0.f;
    erhat[p] = rh;
}

// ---------------- edge kernel v5: swapped-operand MFMA gates (b64 LDS writes) ----------------
// gates computed transposed: lane = edge (lane&15), 4 consecutive channels -> one b64 write.
template<bool HASV>
__global__ __launch_bounds__(128, 4) void k_edge5(
    const int* __restrict__ rowptr, const int* __restrict__ esrc,
    const short* __restrict__ erbf, const float4* __restrict__ erhat,
    const short* __restrict__ pRbf,
    const short* __restrict__ spass, const short* __restrict__ vold,
    float* __restrict__ s, short* __restrict__ vnew) {
    __shared__ __align__(16) short gate_lds[GEB * GLDS_STRIDE];
    __shared__ int   src_lds[GEB];
    __shared__ float4 rh_lds[GEB];
    __shared__ float red[64 * 9];
    int tid = threadIdx.x;
    int lane = tid & 63;
    int wv = tid >> 6;
    int ntb = wv * 12;
    int c0 = lane * 2;
    bf16x8 bfr[12];
    #pragma unroll
    for (int t = 0; t < 12; ++t)
        bfr[t] = *(const bf16x8*)(pRbf + ((size_t)((ntb + t) * 64 + lane)) * 8);
    int e16 = lane & 15;        // edge row within batch (as MFMA col after swap)
    int chb = (lane >> 4) * 4;  // channel base within tile (as MFMA row after swap)
    for (int n = blockIdx.x; n < N_NODES; n += gridDim.x) {
        int p0 = rowptr[n], p1 = rowptr[n + 1];
        float sa0 = 0.f, sa1 = 0.f;
        float va00 = 0.f, va01 = 0.f, va10 = 0.f, va11 = 0.f, va20 = 0.f, va21 = 0.f;
        for (int pb = p0; pb < p1; pb += GEB) {
            int erow = pb + e16;
            if (erow >= p1) erow = p1 - 1;
            bf16x8 afrag = *(const bf16x8*)(erbf + (size_t)erow * 32 + (lane >> 4) * 8);
            if (tid < GEB) {
                int p = pb + tid;
                if (p < p1) { src_lds[tid] = esrc[p]; rh_lds[tid] = erhat[p]; }
            }
            #pragma unroll
            for (int t = 0; t < 12; ++t) {
                f32x4 acc = {0.f, 0.f, 0.f, 0.f};
                // swapped operands: D[ch][edge]
                acc = __builtin_amdgcn_mfma_f32_16x16x32_bf16(bfr[t], afrag, acc, 0, 0, 0);
                int ct = (ntb + t) * 16 + chb;
                short4v w;
                #pragma unroll
                for (int j = 0; j < 4; ++j) w[j] = f2bf(acc[j]);
                *(short4v*)&gate_lds[e16 * GLDS_STRIDE + ct] = w;
            }
            __syncthreads();
            int pe = (pb + GEB < p1) ? pb + GEB : p1;
            for (int p = pb + wv; p < pe; p += 2) {
                int src = src_lds[p - pb];
                float4 rh = rh_lds[p - pb];
                const short* g = gate_lds + (p - pb) * GLDS_STRIDE;
                unsigned ga1 = *(const unsigned*)(g + 128 + c0);
                unsigned ga2 = *(const unsigned*)(g + 256 + c0);
                const short* sp = spass + (size_t)src * D3;
                unsigned sp1 = *(const unsigned*)(sp + 128 + c0);
                unsigned sp2 = *(const unsigned*)(sp + 256 + c0);
                sa0 += bflo(ga1) * bflo(sp1);
                sa1 += bfhi(ga1) * bfhi(sp1);
                float drl = bflo(ga2) * bflo(sp2);
                float drh = bfhi(ga2) * bfhi(sp2);
                if (HASV) {
                    unsigned ga0 = *(const unsigned*)(g + c0);
                    unsigned sp0 = *(const unsigned*)(sp + c0);
                    float dvl = bflo(ga0) * bflo(sp0);
                    float dvh = bfhi(ga0) * bfhi(sp0);
                    const short* vs = vold + (size_t)src * D3;
                    unsigned v0 = *(const unsigned*)(vs + c0);
                    unsigned v1 = *(const unsigned*)(vs + 128 + c0);
                    unsigned v2 = *(const unsigned*)(vs + 256 + c0);
                    va00 += bflo(v0) * dvl + rh.x * drl;
                    va01 += bfhi(v0) * dvh + rh.x * drh;
                    va10 += bflo(v1) * dvl + rh.y * drl;
                    va11 += bfhi(v1) * dvh + rh.y * drh;
                    va20 += bflo(v2) * dvl + rh.z * drl;
                    va21 += bfhi(v2) * dvh + rh.z * drh;
                } else {
                    va00 += rh.x * drl; va01 += rh.x * drh;
                    va10 += rh.y * drl; va11 += rh.y * drh;
                    va20 += rh.z * drl; va21 += rh.z * drh;
                }
            }
            __syncthreads();
        }
        float* rl = red + lane * 9;
        __syncthreads();
        if (wv == 1) {
            rl[0] = sa0; rl[1] = sa1;
            rl[2] = va00; rl[3] = va01; rl[4] = va10; rl[5] = va11; rl[6] = va20; rl[7] = va21;
        }
        __syncthreads();
        if (wv == 0) {
            sa0 += rl[0]; sa1 += rl[1];
            va00 += rl[2]; va01 += rl[3]; va10 += rl[4]; va11 += rl[5]; va20 += rl[6]; va21 += rl[7];
            float2 sv = *(float2*)(s + (size_t)n * D + c0);
            sv.x += sa0; sv.y += sa1;
            *(float2*)(s + (size_t)n * D + c0) = sv;
            size_t vb = (size_t)n * D3;
            if (HASV) {
                unsigned o0 = *(const unsigned*)(vold + vb + c0);
                unsigned o1 = *(const unsigned*)(vold + vb + 128 + c0);
                unsigned o2 = *(const unsigned*)(vold + vb + 256 + c0);
                va00 += bflo(o0); va01 += bfhi(o0);
                va10 += bflo(o1); va11 += bfhi(o1);
                va20 += bflo(o2); va21 += bfhi(o2);
            }
            *(unsigned*)(vnew + vb + c0)       = packbf(va00, va01);
            *(unsigned*)(vnew + vb + 128 + c0) = packbf(va10, va11);
            *(unsigned*)(vnew + vb + 256 + c0) = packbf(va20, va21);
        }
    }
}

// ---------------- V_norm ----------------
__global__ void k_svbuild(const short* __restrict__ Vv, short* __restrict__ Vn) {
    int i = blockIdx.x * 256 + threadIdx.x;   // over N_NODES*D
    int n = i >> 7, c = i & 127;
    float acc = 0.f;
    #pragma unroll
    for (int d = 0; d < 3; ++d) {
        float v = bf2f(Vv[(size_t)(n * 3 + d) * D + c]);
        acc += v * v;
    }
    Vn[i] = f2bf(sqrtf(acc));
}

// ---------------- apply gated update, 2 channels/thread ----------------
__global__ void k_apply(float* __restrict__ s, short* __restrict__ v,
                        const short* __restrict__ Uv, const short* __restrict__ Vv,
                        const short* __restrict__ a_bf) {
    int i = blockIdx.x * 256 + threadIdx.x;   // over N_NODES*64
    int n = i >> 6, c0 = (i & 63) * 2;
    size_t ab = (size_t)n * D3;
    unsigned avv = *(const unsigned*)(a_bf + ab + c0);
    unsigned asv = *(const unsigned*)(a_bf + ab + 128 + c0);
    unsigned ass = *(const unsigned*)(a_bf + ab + 256 + c0);
    float scal0 = 0.f, scal1 = 0.f;
    float u0[3], u1[3];
    #pragma unroll
    for (int d = 0; d < 3; ++d) {
        unsigned uu = *(const unsigned*)(Uv + ab + d * 128 + c0);
        unsigned vv = *(const unsigned*)(Vv + ab + d * 128 + c0);
        u0[d] = bflo(uu); u1[d] = bfhi(uu);
        scal0 += u0[d] * bflo(vv);
        scal1 += u1[d] * bfhi(vv);
    }
    float2 sv = *(float2*)(s + (size_t)n * D + c0);
    sv.x += scal0 * bflo(asv) + bflo(ass);
    sv.y += scal1 * bfhi(asv) + bfhi(ass);
    *(float2*)(s + (size_t)n * D + c0) = sv;
    float a0 = bflo(avv), a1 = bfhi(avv);
    #pragma unroll
    for (int d = 0; d < 3; ++d) {
        unsigned* vp = (unsigned*)(v + ab + d * 128 + c0);
        unsigned old = *vp;
        *vp = packbf(bflo(old) + a0 * u0[d], bfhi(old) + a1 * u1[d]);
    }
}

static inline int g32(int M) { int t = (M + 31) / 32; return (t + 3) / 4; }

extern "C" void kernel_launch(void* const* d_in, const int* in_sizes, int n_in,
                              void* d_out, int out_size, void* d_ws, size_t ws_size,
                              hipStream_t stream) {
    const int*   z         = (const int*)d_in[0];
    const int*   edges     = (const int*)d_in[1];
    const float* r_ij      = (const float*)d_in[2];
    const float* rhat      = (const float*)d_in[3];
    const int*   graph_idx = (const int*)d_in[4];
    const float* emb       = (const float*)d_in[5];
    const float* msg_w1    = (const float*)d_in[6];
    const float* msg_b1    = (const float*)d_in[7];
    const float* msg_w2    = (const float*)d_in[8];
    const float* msg_b2    = (const float*)d_in[9];
    const float* rbf_w     = (const float*)d_in[10];
    const float* rbf_b     = (const float*)d_in[11];
    const float* upd_U     = (const float*)d_in[12];
    const float* upd_V     = (const float*)d_in[13];
    const float* upd_w1    = (const float*)d_in[14];
    const float* upd_b1    = (const float*)d_in[15];
    const float* upd_w2    = (const float*)d_in[16];
    const float* upd_b2    = (const float*)d_in[17];
    const float* blue_w1   = (const float*)d_in[18];
    const float* blue_b1   = (const float*)d_in[19];
    const float* blue_w2   = (const float*)d_in[20];
    const float* blue_b2   = (const float*)d_in[21];
    float* out = (float*)d_out;

    char* ws = (char*)d_ws;
    size_t off = 0;
    auto alloc = [&](size_t bytes) { void* p = ws + off; off += (bytes + 255) & ~(size_t)255; return p; };

    float* s      = (float*)alloc((size_t)N_NODES * D * 4);            // 25.6 MB
    short* bufV0  = (short*)alloc((size_t)N_NODES * D3 * 2);           // 38.4 MB
    short* bufV1  = (short*)alloc((size_t)N_NODES * D3 * 2);           // 38.4 MB
    short* shrd   = (short*)alloc((size_t)N_NODES * D3 * 2);           // 38.4 MB: s_pass -> a
    short* VnBuf  = (short*)alloc((size_t)N_NODES * D * 2);            // 12.8 MB (V_norm)
    short* Vv     = (short*)alloc((size_t)N_NODES * D3 * 2);           // 38.4 MB
    // edge tables
    int*    esrc   = (int*)alloc((size_t)N_EDGES * 4);                 // 1.6 MB
    short*  erbf   = (short*)alloc((size_t)N_EDGES * 32 * 2);          // 25.6 MB
    float4* erhat  = (float4*)alloc((size_t)N_EDGES * 16);             // 6.4 MB
    int*    rowptr = (int*)alloc((size_t)(N_NODES + 1) * 4);
    int*    cnt    = (int*)alloc((size_t)N_NODES * 4);                 // hist then cursor

    // packed weights
    short* pBlue = (short*)alloc(16384 * 2);
    short* pRbfAll = (short*)alloc((size_t)3 * 12288 * 2);
    short* pMsgW1[3]; short* pMsgW2[3]; short* pUV[3]; short* pUpdW1[3]; short* pUpdW2[3];
    for (int i = 0; i < 3; ++i) {
        pMsgW1[i] = (short*)alloc(16384 * 2);
        pMsgW2[i] = (short*)alloc(49152 * 2);
        pUV[i]    = (short*)alloc(32768 * 2);   // U tiles then V tiles
        pUpdW1[i] = (short*)alloc(32768 * 2);
        pUpdW2[i] = (short*)alloc(49152 * 2);
    }

    // ---- all GEMM-weight packs in one dispatch ----
    PackJobs jobs;
    jobs.njobs = 0;
    int bacc = 0;
    auto addjob = [&](const float* W, short* P, int K, int N) {
        int j = jobs.njobs++;
        jobs.W[j] = W; jobs.P[j] = P; jobs.K[j] = K; jobs.N[j] = N;
        jobs.boff[j] = bacc;
        int total = (N / 16) * (K / 32) * 64;
        bacc += (total + 255) / 256;
        jobs.boff[j + 1] = bacc;
    };
    addjob(blue_w1, pBlue, 128, 128);
    for (int i = 0; i < 3; ++i) {
        addjob(msg_w1 + (size_t)i * D * D,     pMsgW1[i], 128, 128);
        addjob(msg_w2 + (size_t)i * D * D3,    pMsgW2[i], 128, 384);
        addjob(upd_U  + (size_t)i * D * D,     pUV[i],          128, 128);
        addjob(upd_V  + (size_t)i * D * D,     pUV[i] + 16384,  128, 128);
        addjob(upd_w1 + (size_t)i * 2 * D * D, pUpdW1[i], 256, 128);
        addjob(upd_w2 + (size_t)i * D * D3,    pUpdW2[i], 128, 384);
    }
    k_packall<<<bacc, 256, 0, stream>>>(jobs);
    k_packrbf<<<18, 256, 0, stream>>>(rbf_w, rbf_b, pRbfAll);

    // ---- edge sort precompute (once per launch) ----
    hipMemsetAsync(cnt, 0, (size_t)N_NODES * 4, stream);
    k_hist<<<(N_EDGES + 255) / 256, 256, 0, stream>>>(edges, cnt);
    k_scanall<<<1, 1024, 0, stream>>>(cnt, rowptr);   // also resets cnt for cursor
    k_scatter<<<(N_EDGES + 255) / 256, 256, 0, stream>>>(edges, r_ij, rhat, rowptr, cnt,
                                                         esrc, erbf, erhat);

    // ---- state init ----
    hipMemsetAsync(d_out, 0, (size_t)out_size * sizeof(float), stream);
    k_embed<<<(N_NODES * D) / 256, 256, 0, stream>>>(z, emb, s);

    const int gN  = g32(N_NODES);
    const int gN3 = g32(N_NODES * 3);

    for (int i = 0; i < 3; ++i) {
        short* vstate = (i & 1) ? bufV1 : bufV0;   // current v (bf16)
        short* vscr   = (i & 1) ? bufV0 : bufV1;   // next v
        // s_pass = silu(s @ msg_w1 + b1) @ msg_w2 + b2   [fused 2-layer MLP]
        k_mlp2<128, 1><<<gN, 256, 0, stream>>>(
            s, nullptr, pMsgW1[i], msg_b1 + (size_t)i * D,
            pMsgW2[i], msg_b2 + (size_t)i * D3, shrd, N_NODES);
        // segment-sum edge gather with MFMA gates: s += ds ; vscr = vstate + dv
        if (i == 0)
            k_edge5<false><<<4096, 128, 0, stream>>>(rowptr, esrc, erbf, erhat,
                                                     pRbfAll, shrd, vstate, s, vscr);
        else
            k_edge5<true><<<4096, 128, 0, stream>>>(rowptr, esrc, erbf, erhat,
                                                    pRbfAll + (size_t)i * 12288,
                                                    shrd, vstate, s, vscr);
        // Uv (into dead vstate buffer) and Vv in ONE GEMM (single A read)
        k_gemmUV<<<gN3, 256, 0, stream>>>(vscr, pUV[i], vstate, Vv, N_NODES * 3);
        // V_norm -> VnBuf
        k_svbuild<<<(N_NODES * D) / 256, 256, 0, stream>>>(Vv, VnBuf);
        // a = silu([Vn | s] @ upd_w1 + b1) @ upd_w2 + b2   [fused 2-layer MLP]
        k_mlp2<256, 2><<<gN, 256, 0, stream>>>(
            VnBuf, s, pUpdW1[i], upd_b1 + (size_t)i * D,
            pUpdW2[i], upd_b2 + (size_t)i * D3, shrd, N_NODES);
        // gated update of s and v (in place on vscr), 2 ch/thread
        k_apply<<<(N_NODES * 64) / 256, 256, 0, stream>>>(s, vscr, vstate, Vv, shrd);
    }

    // fused readout
    k_bluefused<<<gN, 256, 0, stream>>>(s, pBlue, blue_b1, blue_w2, blue_b2,
                                        graph_idx, out, N_NODES);
}

// Round 14
// 986.250 us; speedup vs baseline: 1.0370x; 1.0370x over previous
//
#include <hip/hip_runtime.h>
#include <hip/hip_bf16.h>
#include <math.h>

#define N_NODES 50000
#define N_EDGES 400000
#define N_GRAPHS 2500
#define D 128
#define D3 384
#define N_RBF 20
#define R_CUT 5.0f
#define PI_F 3.14159265358979f
#define GEB 16   // gate edge batch (one MFMA row-block)
#define GLDS_STRIDE 388  // 776 B row stride: mult of 8 for b64 writes

typedef __attribute__((ext_vector_type(8))) short bf16x8;
typedef __attribute__((ext_vector_type(4))) short short4v;
typedef __attribute__((ext_vector_type(4))) float f32x4;

__device__ __forceinline__ float silu_f(float x) {
    return x / (1.0f + __expf(-x));
}
__device__ __forceinline__ short f2bf(float x) {
    union { float f; unsigned u; } v; v.f = x;
    unsigned r = (v.u + 0x7FFFu + ((v.u >> 16) & 1u)) >> 16;
    return (short)r;
}
__device__ __forceinline__ float bf2f(short x) {
    union { unsigned u; float f; } v; v.u = ((unsigned)(unsigned short)x) << 16;
    return v.f;
}
__device__ __forceinline__ float bflo(unsigned u) {
    union { unsigned x; float f; } v; v.x = u << 16; return v.f;
}
__device__ __forceinline__ float bfhi(unsigned u) {
    union { unsigned x; float f; } v; v.x = u & 0xFFFF0000u; return v.f;
}
__device__ __forceinline__ unsigned packbf(float a, float b) {
    return ((unsigned)(unsigned short)f2bf(a)) | (((unsigned)(unsigned short)f2bf(b)) << 16);
}

// ---------------- all weight packs in ONE dispatch ----------------
#define MAXJOBS 19
struct PackJobs {
    const float* W[MAXJOBS];
    short* P[MAXJOBS];
    int K[MAXJOBS];
    int N[MAXJOBS];
    int boff[MAXJOBS + 1];
    int njobs;
};
__global__ void k_packall(PackJobs jobs) {
    int b = blockIdx.x;
    int j = 0;
    while (j + 1 < jobs.njobs && b >= jobs.boff[j + 1]) ++j;
    int t = (b - jobs.boff[j]) * 256 + threadIdx.x;
    int K = jobs.K[j], N = jobs.N[j];
    int NKT = K / 32;
    int total = (N / 16) * NKT * 64;
    if (t >= total) return;
    const float* W = jobs.W[j];
    short* P = jobs.P[j];
    int lane = t & 63;
    int kt = (t >> 6) % NKT;
    int nt = (t >> 6) / NKT;
    int k0 = kt * 32 + (lane >> 4) * 8;
    int col = nt * 16 + (lane & 15);
    #pragma unroll
    for (int q = 0; q < 8; ++q)
        P[(size_t)t * 8 + q] = f2bf(W[(size_t)(k0 + q) * N + col]);
}

// pack [rbf_w(20 rows); rbf_b(1 row); zeros] -> frags, 3 blocks in one dispatch
__global__ void k_packrbf(const float* __restrict__ rbf_w, const float* __restrict__ rbf_b,
                          short* __restrict__ P) {
    int t = blockIdx.x * 256 + threadIdx.x;
    if (t >= 3 * 1536) return;
    int i = t / 1536;
    int r = t - i * 1536;        // nt*64 + lane
    int lane = r & 63;
    int nt = r >> 6;
    int col = nt * 16 + (lane & 15);
    int k0 = (lane >> 4) * 8;
    const float* W = rbf_w + (size_t)i * N_RBF * D3;
    const float* B = rbf_b + (size_t)i * D3;
    short* out = P + (size_t)i * 12288 + (size_t)r * 8;
    #pragma unroll
    for (int q = 0; q < 8; ++q) {
        int k = k0 + q;
        float v = (k < N_RBF) ? W[(size_t)k * D3 + col] : ((k == N_RBF) ? B[col] : 0.0f);
        out[q] = f2bf(v);
    }
}

// ---------------- fused two-layer MLP: Cout = silu(A@W1+b1)@W2+b2 ----------------
// stage1: Kx128 GEMM + silu -> wave-private LDS tile; stage2: 128x384 GEMM from LDS.
// Row-major epilogue (R12-proven: contiguous 32B per 16-lane group).
// AMODE1: 1 = A f32 ; 2 = A1 bf16 (k<128) + A2 f32 (k>=128)
template<int K1, int AMODE1>
__global__ __launch_bounds__(256) void k_mlp2(const void* __restrict__ Aptr,
                                              const void* __restrict__ A2ptr,
                                              const short* __restrict__ Bp1,
                                              const float* __restrict__ b1,
                                              const short* __restrict__ Bp2,
                                              const float* __restrict__ b2,
                                              short* __restrict__ Cout, int M) {
    constexpr int NKT1 = K1 / 32;
    __shared__ __align__(16) short h_lds[4][32][136];  // 34.8 KB, stride 272 B
    int lane = threadIdx.x & 63, wv = threadIdx.x >> 6;
    int tile = blockIdx.x * 4 + wv;
    int base = tile * 32;
    if (base >= M) return;
    bool has2 = (base + 16 < M);
    int r16 = lane & 15;
    int kgrp = (lane >> 4) * 8;
    int arow0 = base + r16;
    int arow1 = has2 ? (base + 16 + r16) : arow0;

    bf16x8 a0[NKT1], a1[NKT1];
    #pragma unroll
    for (int ss = 0; ss < 2; ++ss) {
        int arow = ss ? arow1 : arow0;
        bf16x8* a = ss ? a1 : a0;
        if (AMODE1 == 1) {
            const float* A = (const float*)Aptr + (size_t)arow * K1 + kgrp;
            #pragma unroll
            for (int kt = 0; kt < NKT1; ++kt)
                #pragma unroll
                for (int j = 0; j < 8; ++j) a[kt][j] = f2bf(A[kt * 32 + j]);
        } else {
            const short* A1 = (const short*)Aptr + (size_t)arow * 128 + kgrp;
            const float* A2 = (const float*)A2ptr + (size_t)arow * 128 + kgrp;
            #pragma unroll
            for (int kt = 0; kt < 4 && kt < NKT1; ++kt) a[kt] = *(const bf16x8*)(A1 + kt * 32);
            #pragma unroll
            for (int kt = 4; kt < NKT1; ++kt)
                #pragma unroll
                for (int j = 0; j < 8; ++j) a[kt][j] = f2bf(A2[(kt - 4) * 32 + j]);
        }
    }

    int rloc = (lane >> 4) * 4;
    int ccol = lane & 15;
    const bf16x8* Bv1 = (const bf16x8*)Bp1;
    #pragma unroll
    for (int nt = 0; nt < 8; ++nt) {
        f32x4 acc0 = {0.f, 0.f, 0.f, 0.f};
        f32x4 acc1 = {0.f, 0.f, 0.f, 0.f};
        #pragma unroll
        for (int kt = 0; kt < NKT1; ++kt) {
            bf16x8 b = Bv1[(nt * NKT1 + kt) * 64 + lane];
            acc0 = __builtin_amdgcn_mfma_f32_16x16x32_bf16(a0[kt], b, acc0, 0, 0, 0);
            acc1 = __builtin_amdgcn_mfma_f32_16x16x32_bf16(a1[kt], b, acc1, 0, 0, 0);
        }
        int col = nt * 16 + ccol;
        float bs = b1[col];
        #pragma unroll
        for (int j = 0; j < 4; ++j) {
            h_lds[wv][rloc + j][col]      = f2bf(silu_f(acc0[j] + bs));
            h_lds[wv][16 + rloc + j][col] = f2bf(silu_f(acc1[j] + bs));
        }
    }
    // wave-local LDS: compiler inserts lgkmcnt waits; no barrier needed.
    bf16x8 ha0[4], ha1[4];
    #pragma unroll
    for (int kt = 0; kt < 4; ++kt) {
        ha0[kt] = *(const bf16x8*)&h_lds[wv][r16][kt * 32 + kgrp];
        ha1[kt] = *(const bf16x8*)&h_lds[wv][16 + r16][kt * 32 + kgrp];
    }
    const bf16x8* Bv2 = (const bf16x8*)Bp2;
    #pragma unroll
    for (int nt = 0; nt < 24; ++nt) {
        f32x4 acc0 = {0.f, 0.f, 0.f, 0.f};
        f32x4 acc1 = {0.f, 0.f, 0.f, 0.f};
        #pragma unroll
        for (int kt = 0; kt < 4; ++kt) {
            bf16x8 b = Bv2[(nt * 4 + kt) * 64 + lane];
            acc0 = __builtin_amdgcn_mfma_f32_16x16x32_bf16(ha0[kt], b, acc0, 0, 0, 0);
            acc1 = __builtin_amdgcn_mfma_f32_16x16x32_bf16(ha1[kt], b, acc1, 0, 0, 0);
        }
        int col = nt * 16 + ccol;
        float bs = b2[col];
        #pragma unroll
        for (int j = 0; j < 4; ++j)
            Cout[(size_t)(base + rloc + j) * D3 + col] = f2bf(acc0[j] + bs);
        if (has2) {
            #pragma unroll
            for (int j = 0; j < 4; ++j)
                Cout[(size_t)(base + 16 + rloc + j) * D3 + col] = f2bf(acc1[j] + bs);
        }
    }
}

// ---------------- fused U/V GEMM (32-row tile, row-major epilogue) ----------------
__global__ __launch_bounds__(256) void k_gemmUV(const short* __restrict__ A,
                                                const short* __restrict__ Bp,
                                                short* __restrict__ Cu,
                                                short* __restrict__ Cv, int M) {
    int lane = threadIdx.x & 63, wv = threadIdx.x >> 6;
    int tile = blockIdx.x * 4 + wv;
    int base = tile * 32;
    if (base >= M) return;
    bool has2 = (base + 16 < M);
    int r16 = lane & 15;
    int kgrp = (lane >> 4) * 8;
    const short* Ar0 = A + (size_t)(base + r16) * 128 + kgrp;
    const short* Ar1 = A + (size_t)((has2 ? base + 16 : base) + r16) * 128 + kgrp;
    bf16x8 a0[4], a1[4];
    #pragma unroll
    for (int kt = 0; kt < 4; ++kt) {
        a0[kt] = *(const bf16x8*)(Ar0 + kt * 32);
        a1[kt] = *(const bf16x8*)(Ar1 + kt * 32);
    }
    int crow0 = base + (lane >> 4) * 4;
    int ccol = lane & 15;
    const bf16x8* Bv = (const bf16x8*)Bp;
    #pragma unroll
    for (int nt = 0; nt < 16; ++nt) {
        f32x4 acc0 = {0.f, 0.f, 0.f, 0.f};
        f32x4 acc1 = {0.f, 0.f, 0.f, 0.f};
        #pragma unroll
        for (int kt = 0; kt < 4; ++kt) {
            bf16x8 b = Bv[(nt * 4 + kt) * 64 + lane];
            acc0 = __builtin_amdgcn_mfma_f32_16x16x32_bf16(a0[kt], b, acc0, 0, 0, 0);
            acc1 = __builtin_amdgcn_mfma_f32_16x16x32_bf16(a1[kt], b, acc1, 0, 0, 0);
        }
        int col = nt * 16 + ccol;
        short* C = (col < 128) ? Cu : Cv;
        int cc = col & 127;
        #pragma unroll
        for (int j = 0; j < 4; ++j)
            C[(size_t)(crow0 + j) * 128 + cc] = f2bf(acc0[j]);
        if (has2) {
            #pragma unroll
            for (int j = 0; j < 4; ++j)
                C[(size_t)(crow0 + 16 + j) * 128 + cc] = f2bf(acc1[j]);
        }
    }
}

// ---------------- fused readout: h = silu(s@W1+b1); out[g] += dot(h, w2) + b2 ----------------
__global__ __launch_bounds__(256) void k_bluefused(const float* __restrict__ s,
                                                   const short* __restrict__ Bp,
                                                   const float* __restrict__ b1,
                                                   const float* __restrict__ w2,
                                                   const float* __restrict__ b2,
                                                   const int* __restrict__ graph_idx,
                                                   float* __restrict__ out, int M) {
    int lane = threadIdx.x & 63, wv = threadIdx.x >> 6;
    int tile = blockIdx.x * 4 + wv;
    int base = tile * 32;
    if (base >= M) return;
    bool has2 = (base + 16 < M);
    int r16 = lane & 15;
    int kgrp = (lane >> 4) * 8;
    int arow0 = base + r16;
    int arow1 = has2 ? (base + 16 + r16) : arow0;
    bf16x8 a0[4], a1[4];
    {
        const float* A = s + (size_t)arow0 * 128 + kgrp;
        #pragma unroll
        for (int kt = 0; kt < 4; ++kt)
            #pragma unroll
            for (int j = 0; j < 8; ++j) a0[kt][j] = f2bf(A[kt * 32 + j]);
        const float* B = s + (size_t)arow1 * 128 + kgrp;
        #pragma unroll
        for (int kt = 0; kt < 4; ++kt)
            #pragma unroll
            for (int j = 0; j < 8; ++j) a1[kt][j] = f2bf(B[kt * 32 + j]);
    }
    int crow0 = base + (lane >> 4) * 4;
    int ccol = lane & 15;
    const bf16x8* Bv = (const bf16x8*)Bp;
    float dot0[4] = {0.f, 0.f, 0.f, 0.f};
    float dot1[4] = {0.f, 0.f, 0.f, 0.f};
    #pragma unroll
    for (int nt = 0; nt < 8; ++nt) {
        f32x4 acc0 = {0.f, 0.f, 0.f, 0.f};
        f32x4 acc1 = {0.f, 0.f, 0.f, 0.f};
        #pragma unroll
        for (int kt = 0; kt < 4; ++kt) {
            bf16x8 b = Bv[(nt * 4 + kt) * 64 + lane];
            acc0 = __builtin_amdgcn_mfma_f32_16x16x32_bf16(a0[kt], b, acc0, 0, 0, 0);
            acc1 = __builtin_amdgcn_mfma_f32_16x16x32_bf16(a1[kt], b, acc1, 0, 0, 0);
        }
        int col = nt * 16 + ccol;
        float bs = b1[col], w = w2[col];
        #pragma unroll
        for (int j = 0; j < 4; ++j) {
            dot0[j] += silu_f(acc0[j] + bs) * w;
            dot1[j] += silu_f(acc1[j] + bs) * w;
        }
    }
    #pragma unroll
    for (int m = 1; m <= 8; m <<= 1) {
        #pragma unroll
        for (int j = 0; j < 4; ++j) {
            dot0[j] += __shfl_xor(dot0[j], m, 64);
            dot1[j] += __shfl_xor(dot1[j], m, 64);
        }
    }
    if (ccol == 0) {
        #pragma unroll
        for (int j = 0; j < 4; ++j) {
            int n = crow0 + j;
            atomicAdd(&out[graph_idx[n]], dot0[j] + b2[0]);
        }
        if (has2) {
            #pragma unroll
            for (int j = 0; j < 4; ++j) {
                int n = crow0 + 16 + j;
                atomicAdd(&out[graph_idx[n]], dot1[j] + b2[0]);
            }
        }
    }
}

// ---------------- embed ----------------
__global__ void k_embed(const int* __restrict__ z, const float* __restrict__ emb,
                        float* __restrict__ s) {
    int i = blockIdx.x * blockDim.x + threadIdx.x;
    if (i < N_NODES * D) {
        int n = i >> 7, c = i & 127;
        s[i] = emb[z[n] * D + c];
    }
}

// ---------------- edge-sort precompute ----------------
__global__ void k_hist(const int* __restrict__ edges, int* __restrict__ cnt) {
    int e = blockIdx.x * 256 + threadIdx.x;
    if (e < N_EDGES) atomicAdd(&cnt[edges[2 * e]], 1);
}

// single-dispatch scan: cnt -> rowptr (exclusive), reset cnt for cursor use
#define SCH 49   // ceil(50000/1024)
__global__ __launch_bounds__(1024) void k_scanall(int* __restrict__ cnt,
                                                  int* __restrict__ rowptr) {
    __shared__ int part[1024];
    int t = threadIdx.x;
    int lo = t * SCH;
    int hi = lo + SCH; if (hi > N_NODES) hi = N_NODES;
    int sum = 0;
    for (int i = lo; i < hi; ++i) sum += cnt[i];
    part[t] = sum;
    __syncthreads();
    for (int off = 1; off < 1024; off <<= 1) {
        int v = (t >= off) ? part[t - off] : 0;
        __syncthreads();
        part[t] += v;
        __syncthreads();
    }
    int run = part[t] - sum;   // exclusive prefix
    for (int i = lo; i < hi; ++i) {
        rowptr[i] = run;
        run += cnt[i];
        cnt[i] = 0;            // reset for cursor phase
    }
    if (t == 1023) rowptr[N_NODES] = N_EDGES;
}

// scatter edges into dst-sorted order; per edge: erbf[32] bf16 (rbf*fc, fc, 0...), rhat float4
__global__ void k_scatter(const int* __restrict__ edges, const float* __restrict__ r_ij,
                          const float* __restrict__ rhat, const int* __restrict__ rowptr,
                          int* __restrict__ cursor, int* __restrict__ esrc,
                          short* __restrict__ erbf, float4* __restrict__ erhat) {
    int e = blockIdx.x * 256 + threadIdx.x;
    if (e >= N_EDGES) return;
    int dst = edges[2 * e], src = edges[2 * e + 1];
    int p = rowptr[dst] + atomicAdd(&cursor[dst], 1);
    esrc[p] = src;
    float r = r_ij[e];
    float fc = (r <= R_CUT) ? 0.5f * (cosf(PI_F * r / R_CUT) + 1.0f) : 0.0f;
    float inv_r = 1.0f / r;
    short rec[32];
    #pragma unroll
    for (int k = 0; k < N_RBF; ++k)
        rec[k] = f2bf(sinf((float)(k + 1) * (PI_F / R_CUT) * r) * inv_r * fc);
    rec[20] = f2bf(fc);
    #pragma unroll
    for (int k = 21; k < 32; ++k) rec[k] = 0;
    short* out = erbf + (size_t)p * 32;
    #pragma unroll
    for (int k = 0; k < 32; ++k) out[k] = rec[k];
    float4 rh;
    rh.x = rhat[3 * e]; rh.y = rhat[3 * e + 1]; rh.z = rhat[3 * e + 2]; rh.w = 0.f;
    erhat[p] = rh;
}

// ---------------- edge kernel v5: swapped-operand MFMA gates (b64 LDS writes) ----------------
template<bool HASV>
__global__ __launch_bounds__(128, 4) void k_edge5(
    const int* __restrict__ rowptr, const int* __restrict__ esrc,
    const short* __restrict__ erbf, const float4* __restrict__ erhat,
    const short* __restrict__ pRbf,
    const short* __restrict__ spass, const short* __restrict__ vold,
    float* __restrict__ s, short* __restrict__ vnew) {
    __shared__ __align__(16) short gate_lds[GEB * GLDS_STRIDE];
    __shared__ int   src_lds[GEB];
    __shared__ float4 rh_lds[GEB];
    __shared__ float red[64 * 9];
    int tid = threadIdx.x;
    int lane = tid & 63;
    int wv = tid >> 6;
    int ntb = wv * 12;
    int c0 = lane * 2;
    bf16x8 bfr[12];
    #pragma unroll
    for (int t = 0; t < 12; ++t)
        bfr[t] = *(const bf16x8*)(pRbf + ((size_t)((ntb + t) * 64 + lane)) * 8);
    int e16 = lane & 15;        // edge row within batch (as MFMA col after swap)
    int chb = (lane >> 4) * 4;  // channel base within tile (as MFMA row after swap)
    for (int n = blockIdx.x; n < N_NODES; n += gridDim.x) {
        int p0 = rowptr[n], p1 = rowptr[n + 1];
        float sa0 = 0.f, sa1 = 0.f;
        float va00 = 0.f, va01 = 0.f, va10 = 0.f, va11 = 0.f, va20 = 0.f, va21 = 0.f;
        for (int pb = p0; pb < p1; pb += GEB) {
            int erow = pb + e16;
            if (erow >= p1) erow = p1 - 1;
            bf16x8 afrag = *(const bf16x8*)(erbf + (size_t)erow * 32 + (lane >> 4) * 8);
            if (tid < GEB) {
                int p = pb + tid;
                if (p < p1) { src_lds[tid] = esrc[p]; rh_lds[tid] = erhat[p]; }
            }
            #pragma unroll
            for (int t = 0; t < 12; ++t) {
                f32x4 acc = {0.f, 0.f, 0.f, 0.f};
                // swapped operands: D[ch][edge]
                acc = __builtin_amdgcn_mfma_f32_16x16x32_bf16(bfr[t], afrag, acc, 0, 0, 0);
                int ct = (ntb + t) * 16 + chb;
                short4v w;
                #pragma unroll
                for (int j = 0; j < 4; ++j) w[j] = f2bf(acc[j]);
                *(short4v*)&gate_lds[e16 * GLDS_STRIDE + ct] = w;
            }
            __syncthreads();
            int pe = (pb + GEB < p1) ? pb + GEB : p1;
            for (int p = pb + wv; p < pe; p += 2) {
                int src = src_lds[p - pb];
                float4 rh = rh_lds[p - pb];
                const short* g = gate_lds + (p - pb) * GLDS_STRIDE;
                unsigned ga1 = *(const unsigned*)(g + 128 + c0);
                unsigned ga2 = *(const unsigned*)(g + 256 + c0);
                const short* sp = spass + (size_t)src * D3;
                unsigned sp1 = *(const unsigned*)(sp + 128 + c0);
                unsigned sp2 = *(const unsigned*)(sp + 256 + c0);
                sa0 += bflo(ga1) * bflo(sp1);
                sa1 += bfhi(ga1) * bfhi(sp1);
                float drl = bflo(ga2) * bflo(sp2);
                float drh = bfhi(ga2) * bfhi(sp2);
                if (HASV) {
                    unsigned ga0 = *(const unsigned*)(g + c0);
                    unsigned sp0 = *(const unsigned*)(sp + c0);
                    float dvl = bflo(ga0) * bflo(sp0);
                    float dvh = bfhi(ga0) * bfhi(sp0);
                    const short* vs = vold + (size_t)src * D3;
                    unsigned v0 = *(const unsigned*)(vs + c0);
                    unsigned v1 = *(const unsigned*)(vs + 128 + c0);
                    unsigned v2 = *(const unsigned*)(vs + 256 + c0);
                    va00 += bflo(v0) * dvl + rh.x * drl;
                    va01 += bfhi(v0) * dvh + rh.x * drh;
                    va10 += bflo(v1) * dvl + rh.y * drl;
                    va11 += bfhi(v1) * dvh + rh.y * drh;
                    va20 += bflo(v2) * dvl + rh.z * drl;
                    va21 += bfhi(v2) * dvh + rh.z * drh;
                } else {
                    va00 += rh.x * drl; va01 += rh.x * drh;
                    va10 += rh.y * drl; va11 += rh.y * drh;
                    va20 += rh.z * drl; va21 += rh.z * drh;
                }
            }
            __syncthreads();
        }
        float* rl = red + lane * 9;
        __syncthreads();
        if (wv == 1) {
            rl[0] = sa0; rl[1] = sa1;
            rl[2] = va00; rl[3] = va01; rl[4] = va10; rl[5] = va11; rl[6] = va20; rl[7] = va21;
        }
        __syncthreads();
        if (wv == 0) {
            sa0 += rl[0]; sa1 += rl[1];
            va00 += rl[2]; va01 += rl[3]; va10 += rl[4]; va11 += rl[5]; va20 += rl[6]; va21 += rl[7];
            float2 sv = *(float2*)(s + (size_t)n * D + c0);
            sv.x += sa0; sv.y += sa1;
            *(float2*)(s + (size_t)n * D + c0) = sv;
            size_t vb = (size_t)n * D3;
            if (HASV) {
                unsigned o0 = *(const unsigned*)(vold + vb + c0);
                unsigned o1 = *(const unsigned*)(vold + vb + 128 + c0);
                unsigned o2 = *(const unsigned*)(vold + vb + 256 + c0);
                va00 += bflo(o0); va01 += bfhi(o0);
                va10 += bflo(o1); va11 += bfhi(o1);
                va20 += bflo(o2); va21 += bfhi(o2);
            }
            *(unsigned*)(vnew + vb + c0)       = packbf(va00, va01);
            *(unsigned*)(vnew + vb + 128 + c0) = packbf(va10, va11);
            *(unsigned*)(vnew + vb + 256 + c0) = packbf(va20, va21);
        }
    }
}

// ---------------- V_norm ----------------
__global__ void k_svbuild(const short* __restrict__ Vv, short* __restrict__ Vn) {
    int i = blockIdx.x * 256 + threadIdx.x;   // over N_NODES*D
    int n = i >> 7, c = i & 127;
    float acc = 0.f;
    #pragma unroll
    for (int d = 0; d < 3; ++d) {
        float v = bf2f(Vv[(size_t)(n * 3 + d) * D + c]);
        acc += v * v;
    }
    Vn[i] = f2bf(sqrtf(acc));
}

// ---------------- apply gated update, 2 channels/thread ----------------
__global__ void k_apply(float* __restrict__ s, short* __restrict__ v,
                        const short* __restrict__ Uv, const short* __restrict__ Vv,
                        const short* __restrict__ a_bf) {
    int i = blockIdx.x * 256 + threadIdx.x;   // over N_NODES*64
    int n = i >> 6, c0 = (i & 63) * 2;
    size_t ab = (size_t)n * D3;
    unsigned avv = *(const unsigned*)(a_bf + ab + c0);
    unsigned asv = *(const unsigned*)(a_bf + ab + 128 + c0);
    unsigned ass = *(const unsigned*)(a_bf + ab + 256 + c0);
    float scal0 = 0.f, scal1 = 0.f;
    float u0[3], u1[3];
    #pragma unroll
    for (int d = 0; d < 3; ++d) {
        unsigned uu = *(const unsigned*)(Uv + ab + d * 128 + c0);
        unsigned vv = *(const unsigned*)(Vv + ab + d * 128 + c0);
        u0[d] = bflo(uu); u1[d] = bfhi(uu);
        scal0 += u0[d] * bflo(vv);
        scal1 += u1[d] * bfhi(vv);
    }
    float2 sv = *(float2*)(s + (size_t)n * D + c0);
    sv.x += scal0 * bflo(asv) + bflo(ass);
    sv.y += scal1 * bfhi(asv) + bfhi(ass);
    *(float2*)(s + (size_t)n * D + c0) = sv;
    float a0 = bflo(avv), a1 = bfhi(avv);
    #pragma unroll
    for (int d = 0; d < 3; ++d) {
        unsigned* vp = (unsigned*)(v + ab + d * 128 + c0);
        unsigned old = *vp;
        *vp = packbf(bflo(old) + a0 * u0[d], bfhi(old) + a1 * u1[d]);
    }
}

static inline int g32(int M) { int t = (M + 31) / 32; return (t + 3) / 4; }

extern "C" void kernel_launch(void* const* d_in, const int* in_sizes, int n_in,
                              void* d_out, int out_size, void* d_ws, size_t ws_size,
                              hipStream_t stream) {
    const int*   z         = (const int*)d_in[0];
    const int*   edges     = (const int*)d_in[1];
    const float* r_ij      = (const float*)d_in[2];
    const float* rhat      = (const float*)d_in[3];
    const int*   graph_idx = (const int*)d_in[4];
    const float* emb       = (const float*)d_in[5];
    const float* msg_w1    = (const float*)d_in[6];
    const float* msg_b1    = (const float*)d_in[7];
    const float* msg_w2    = (const float*)d_in[8];
    const float* msg_b2    = (const float*)d_in[9];
    const float* rbf_w     = (const float*)d_in[10];
    const float* rbf_b     = (const float*)d_in[11];
    const float* upd_U     = (const float*)d_in[12];
    const float* upd_V     = (const float*)d_in[13];
    const float* upd_w1    = (const float*)d_in[14];
    const float* upd_b1    = (const float*)d_in[15];
    const float* upd_w2    = (const float*)d_in[16];
    const float* upd_b2    = (const float*)d_in[17];
    const float* blue_w1   = (const float*)d_in[18];
    const float* blue_b1   = (const float*)d_in[19];
    const float* blue_w2   = (const float*)d_in[20];
    const float* blue_b2   = (const float*)d_in[21];
    float* out = (float*)d_out;

    char* ws = (char*)d_ws;
    size_t off = 0;
    auto alloc = [&](size_t bytes) { void* p = ws + off; off += (bytes + 255) & ~(size_t)255; return p; };

    float* s      = (float*)alloc((size_t)N_NODES * D * 4);            // 25.6 MB
    short* bufV0  = (short*)alloc((size_t)N_NODES * D3 * 2);           // 38.4 MB
    short* bufV1  = (short*)alloc((size_t)N_NODES * D3 * 2);           // 38.4 MB
    short* shrd   = (short*)alloc((size_t)N_NODES * D3 * 2);           // 38.4 MB: s_pass -> a
    short* VnBuf  = (short*)alloc((size_t)N_NODES * D * 2);            // 12.8 MB (V_norm)
    short* Vv     = (short*)alloc((size_t)N_NODES * D3 * 2);           // 38.4 MB
    // edge tables
    int*    esrc   = (int*)alloc((size_t)N_EDGES * 4);                 // 1.6 MB
    short*  erbf   = (short*)alloc((size_t)N_EDGES * 32 * 2);          // 25.6 MB
    float4* erhat  = (float4*)alloc((size_t)N_EDGES * 16);             // 6.4 MB
    int*    rowptr = (int*)alloc((size_t)(N_NODES + 1) * 4);
    int*    cnt    = (int*)alloc((size_t)N_NODES * 4);                 // hist then cursor

    // packed weights
    short* pBlue = (short*)alloc(16384 * 2);
    short* pRbfAll = (short*)alloc((size_t)3 * 12288 * 2);
    short* pMsgW1[3]; short* pMsgW2[3]; short* pUV[3]; short* pUpdW1[3]; short* pUpdW2[3];
    for (int i = 0; i < 3; ++i) {
        pMsgW1[i] = (short*)alloc(16384 * 2);
        pMsgW2[i] = (short*)alloc(49152 * 2);
        pUV[i]    = (short*)alloc(32768 * 2);   // U tiles then V tiles
        pUpdW1[i] = (short*)alloc(32768 * 2);
        pUpdW2[i] = (short*)alloc(49152 * 2);
    }

    // ---- all GEMM-weight packs in one dispatch ----
    PackJobs jobs;
    jobs.njobs = 0;
    int bacc = 0;
    auto addjob = [&](const float* W, short* P, int K, int N) {
        int j = jobs.njobs++;
        jobs.W[j] = W; jobs.P[j] = P; jobs.K[j] = K; jobs.N[j] = N;
        jobs.boff[j] = bacc;
        int total = (N / 16) * (K / 32) * 64;
        bacc += (total + 255) / 256;
        jobs.boff[j + 1] = bacc;
    };
    addjob(blue_w1, pBlue, 128, 128);
    for (int i = 0; i < 3; ++i) {
        addjob(msg_w1 + (size_t)i * D * D,     pMsgW1[i], 128, 128);
        addjob(msg_w2 + (size_t)i * D * D3,    pMsgW2[i], 128, 384);
        addjob(upd_U  + (size_t)i * D * D,     pUV[i],          128, 128);
        addjob(upd_V  + (size_t)i * D * D,     pUV[i] + 16384,  128, 128);
        addjob(upd_w1 + (size_t)i * 2 * D * D, pUpdW1[i], 256, 128);
        addjob(upd_w2 + (size_t)i * D * D3,    pUpdW2[i], 128, 384);
    }
    k_packall<<<bacc, 256, 0, stream>>>(jobs);
    k_packrbf<<<18, 256, 0, stream>>>(rbf_w, rbf_b, pRbfAll);

    // ---- edge sort precompute (once per launch) ----
    hipMemsetAsync(cnt, 0, (size_t)N_NODES * 4, stream);
    k_hist<<<(N_EDGES + 255) / 256, 256, 0, stream>>>(edges, cnt);
    k_scanall<<<1, 1024, 0, stream>>>(cnt, rowptr);   // also resets cnt for cursor
    k_scatter<<<(N_EDGES + 255) / 256, 256, 0, stream>>>(edges, r_ij, rhat, rowptr, cnt,
                                                         esrc, erbf, erhat);

    // ---- state init ----
    hipMemsetAsync(d_out, 0, (size_t)out_size * sizeof(float), stream);
    k_embed<<<(N_NODES * D) / 256, 256, 0, stream>>>(z, emb, s);

    const int gN  = g32(N_NODES);
    const int gN3 = g32(N_NODES * 3);

    for (int i = 0; i < 3; ++i) {
        short* vstate = (i & 1) ? bufV1 : bufV0;   // current v (bf16)
        short* vscr   = (i & 1) ? bufV0 : bufV1;   // next v
        // s_pass = silu(s @ msg_w1 + b1) @ msg_w2 + b2   [fused 2-layer MLP]
        k_mlp2<128, 1><<<gN, 256, 0, stream>>>(
            s, nullptr, pMsgW1[i], msg_b1 + (size_t)i * D,
            pMsgW2[i], msg_b2 + (size_t)i * D3, shrd, N_NODES);
        // segment-sum edge gather with MFMA gates: s += ds ; vscr = vstate + dv
        if (i == 0)
            k_edge5<false><<<4096, 128, 0, stream>>>(rowptr, esrc, erbf, erhat,
                                                     pRbfAll, shrd, vstate, s, vscr);
        else
            k_edge5<true><<<4096, 128, 0, stream>>>(rowptr, esrc, erbf, erhat,
                                                    pRbfAll + (size_t)i * 12288,
                                                    shrd, vstate, s, vscr);
        // Uv (into dead vstate buffer) and Vv in ONE GEMM (single A read)
        k_gemmUV<<<gN3, 256, 0, stream>>>(vscr, pUV[i], vstate, Vv, N_NODES * 3);
        // V_norm -> VnBuf
        k_svbuild<<<(N_NODES * D) / 256, 256, 0, stream>>>(Vv, VnBuf);
        // a = silu([Vn | s] @ upd_w1 + b1) @ upd_w2 + b2   [fused 2-layer MLP]
        k_mlp2<256, 2><<<gN, 256, 0, stream>>>(
            VnBuf, s, pUpdW1[i], upd_b1 + (size_t)i * D,
            pUpdW2[i], upd_b2 + (size_t)i * D3, shrd, N_NODES);
        // gated update of s and v (in place on vscr), 2 ch/thread
        k_apply<<<(N_NODES * 64) / 256, 256, 0, stream>>>(s, vscr, vstate, Vv, shrd);
    }

    // fused readout
    k_bluefused<<<gN, 256, 0, stream>>>(s, pBlue, blue_b1, blue_w2, blue_b2,
                                        graph_idx, out, N_NODES);
}

// Round 15
// 976.171 us; speedup vs baseline: 1.0477x; 1.0103x over previous
//
#include <hip/hip_runtime.h>
#include <hip/hip_bf16.h>
#include <math.h>

#define N_NODES 50000
#define N_EDGES 400000
#define N_GRAPHS 2500
#define D 128
#define D3 384
#define N_RBF 20
#define R_CUT 5.0f
#define PI_F 3.14159265358979f
#define GEB 16   // gate edge batch (one MFMA row-block)
#define GLDS_STRIDE 388  // 776 B row stride: mult of 8 for b64 writes

typedef __attribute__((ext_vector_type(8))) short bf16x8;
typedef __attribute__((ext_vector_type(4))) short short4v;
typedef __attribute__((ext_vector_type(4))) float f32x4;

__device__ __forceinline__ float silu_f(float x) {
    return x / (1.0f + __expf(-x));
}
__device__ __forceinline__ short f2bf(float x) {
    union { float f; unsigned u; } v; v.f = x;
    unsigned r = (v.u + 0x7FFFu + ((v.u >> 16) & 1u)) >> 16;
    return (short)r;
}
__device__ __forceinline__ float bf2f(short x) {
    union { unsigned u; float f; } v; v.u = ((unsigned)(unsigned short)x) << 16;
    return v.f;
}
__device__ __forceinline__ float bflo(unsigned u) {
    union { unsigned x; float f; } v; v.x = u << 16; return v.f;
}
__device__ __forceinline__ float bfhi(unsigned u) {
    union { unsigned x; float f; } v; v.x = u & 0xFFFF0000u; return v.f;
}
__device__ __forceinline__ unsigned packbf(float a, float b) {
    return ((unsigned)(unsigned short)f2bf(a)) | (((unsigned)(unsigned short)f2bf(b)) << 16);
}

// ---------------- all weight packs in ONE dispatch ----------------
#define MAXJOBS 19
struct PackJobs {
    const float* W[MAXJOBS];
    short* P[MAXJOBS];
    int K[MAXJOBS];
    int N[MAXJOBS];
    int boff[MAXJOBS + 1];
    int njobs;
};
__global__ void k_packall(PackJobs jobs) {
    int b = blockIdx.x;
    int j = 0;
    while (j + 1 < jobs.njobs && b >= jobs.boff[j + 1]) ++j;
    int t = (b - jobs.boff[j]) * 256 + threadIdx.x;
    int K = jobs.K[j], N = jobs.N[j];
    int NKT = K / 32;
    int total = (N / 16) * NKT * 64;
    if (t >= total) return;
    const float* W = jobs.W[j];
    short* P = jobs.P[j];
    int lane = t & 63;
    int kt = (t >> 6) % NKT;
    int nt = (t >> 6) / NKT;
    int k0 = kt * 32 + (lane >> 4) * 8;
    int col = nt * 16 + (lane & 15);
    #pragma unroll
    for (int q = 0; q < 8; ++q)
        P[(size_t)t * 8 + q] = f2bf(W[(size_t)(k0 + q) * N + col]);
}

// pack [rbf_w(20 rows); rbf_b(1 row); zeros] -> frags, 3 blocks in one dispatch
__global__ void k_packrbf(const float* __restrict__ rbf_w, const float* __restrict__ rbf_b,
                          short* __restrict__ P) {
    int t = blockIdx.x * 256 + threadIdx.x;
    if (t >= 3 * 1536) return;
    int i = t / 1536;
    int r = t - i * 1536;        // nt*64 + lane
    int lane = r & 63;
    int nt = r >> 6;
    int col = nt * 16 + (lane & 15);
    int k0 = (lane >> 4) * 8;
    const float* W = rbf_w + (size_t)i * N_RBF * D3;
    const float* B = rbf_b + (size_t)i * D3;
    short* out = P + (size_t)i * 12288 + (size_t)r * 8;
    #pragma unroll
    for (int q = 0; q < 8; ++q) {
        int k = k0 + q;
        float v = (k < N_RBF) ? W[(size_t)k * D3 + col] : ((k == N_RBF) ? B[col] : 0.0f);
        out[q] = f2bf(v);
    }
}

// ---------------- fused two-layer MLP: Cout = silu(A@W1+b1)@W2+b2 ----------------
// stage1: Kx128 GEMM + silu -> wave-private LDS tile; stage2: 128x384 GEMM from LDS.
// Row-major epilogue (R12-proven: contiguous 32B per 16-lane group).
// AMODE1: 1 = A f32 ; 2 = A1 bf16 (k<128) + A2 f32 (k>=128)
template<int K1, int AMODE1>
__global__ __launch_bounds__(256) void k_mlp2(const void* __restrict__ Aptr,
                                              const void* __restrict__ A2ptr,
                                              const short* __restrict__ Bp1,
                                              const float* __restrict__ b1,
                                              const short* __restrict__ Bp2,
                                              const float* __restrict__ b2,
                                              short* __restrict__ Cout, int M) {
    constexpr int NKT1 = K1 / 32;
    __shared__ __align__(16) short h_lds[4][32][136];  // 34.8 KB, stride 272 B
    int lane = threadIdx.x & 63, wv = threadIdx.x >> 6;
    int tile = blockIdx.x * 4 + wv;
    int base = tile * 32;
    if (base >= M) return;
    bool has2 = (base + 16 < M);
    int r16 = lane & 15;
    int kgrp = (lane >> 4) * 8;
    int arow0 = base + r16;
    int arow1 = has2 ? (base + 16 + r16) : arow0;

    bf16x8 a0[NKT1], a1[NKT1];
    #pragma unroll
    for (int ss = 0; ss < 2; ++ss) {
        int arow = ss ? arow1 : arow0;
        bf16x8* a = ss ? a1 : a0;
        if (AMODE1 == 1) {
            const float* A = (const float*)Aptr + (size_t)arow * K1 + kgrp;
            #pragma unroll
            for (int kt = 0; kt < NKT1; ++kt)
                #pragma unroll
                for (int j = 0; j < 8; ++j) a[kt][j] = f2bf(A[kt * 32 + j]);
        } else {
            const short* A1 = (const short*)Aptr + (size_t)arow * 128 + kgrp;
            const float* A2 = (const float*)A2ptr + (size_t)arow * 128 + kgrp;
            #pragma unroll
            for (int kt = 0; kt < 4 && kt < NKT1; ++kt) a[kt] = *(const bf16x8*)(A1 + kt * 32);
            #pragma unroll
            for (int kt = 4; kt < NKT1; ++kt)
                #pragma unroll
                for (int j = 0; j < 8; ++j) a[kt][j] = f2bf(A2[(kt - 4) * 32 + j]);
        }
    }

    int rloc = (lane >> 4) * 4;
    int ccol = lane & 15;
    const bf16x8* Bv1 = (const bf16x8*)Bp1;
    #pragma unroll
    for (int nt = 0; nt < 8; ++nt) {
        f32x4 acc0 = {0.f, 0.f, 0.f, 0.f};
        f32x4 acc1 = {0.f, 0.f, 0.f, 0.f};
        #pragma unroll
        for (int kt = 0; kt < NKT1; ++kt) {
            bf16x8 b = Bv1[(nt * NKT1 + kt) * 64 + lane];
            acc0 = __builtin_amdgcn_mfma_f32_16x16x32_bf16(a0[kt], b, acc0, 0, 0, 0);
            acc1 = __builtin_amdgcn_mfma_f32_16x16x32_bf16(a1[kt], b, acc1, 0, 0, 0);
        }
        int col = nt * 16 + ccol;
        float bs = b1[col];
        #pragma unroll
        for (int j = 0; j < 4; ++j) {
            h_lds[wv][rloc + j][col]      = f2bf(silu_f(acc0[j] + bs));
            h_lds[wv][16 + rloc + j][col] = f2bf(silu_f(acc1[j] + bs));
        }
    }
    // wave-local LDS: compiler inserts lgkmcnt waits; no barrier needed.
    bf16x8 ha0[4], ha1[4];
    #pragma unroll
    for (int kt = 0; kt < 4; ++kt) {
        ha0[kt] = *(const bf16x8*)&h_lds[wv][r16][kt * 32 + kgrp];
        ha1[kt] = *(const bf16x8*)&h_lds[wv][16 + r16][kt * 32 + kgrp];
    }
    const bf16x8* Bv2 = (const bf16x8*)Bp2;
    #pragma unroll
    for (int nt = 0; nt < 24; ++nt) {
        f32x4 acc0 = {0.f, 0.f, 0.f, 0.f};
        f32x4 acc1 = {0.f, 0.f, 0.f, 0.f};
        #pragma unroll
        for (int kt = 0; kt < 4; ++kt) {
            bf16x8 b = Bv2[(nt * 4 + kt) * 64 + lane];
            acc0 = __builtin_amdgcn_mfma_f32_16x16x32_bf16(ha0[kt], b, acc0, 0, 0, 0);
            acc1 = __builtin_amdgcn_mfma_f32_16x16x32_bf16(ha1[kt], b, acc1, 0, 0, 0);
        }
        int col = nt * 16 + ccol;
        float bs = b2[col];
        #pragma unroll
        for (int j = 0; j < 4; ++j)
            Cout[(size_t)(base + rloc + j) * D3 + col] = f2bf(acc0[j] + bs);
        if (has2) {
            #pragma unroll
            for (int j = 0; j < 4; ++j)
                Cout[(size_t)(base + 16 + rloc + j) * D3 + col] = f2bf(acc1[j] + bs);
        }
    }
}

// ---------------- fused U/V GEMM (32-row tile, row-major epilogue) ----------------
__global__ __launch_bounds__(256) void k_gemmUV(const short* __restrict__ A,
                                                const short* __restrict__ Bp,
                                                short* __restrict__ Cu,
                                                short* __restrict__ Cv, int M) {
    int lane = threadIdx.x & 63, wv = threadIdx.x >> 6;
    int tile = blockIdx.x * 4 + wv;
    int base = tile * 32;
    if (base >= M) return;
    bool has2 = (base + 16 < M);
    int r16 = lane & 15;
    int kgrp = (lane >> 4) * 8;
    const short* Ar0 = A + (size_t)(base + r16) * 128 + kgrp;
    const short* Ar1 = A + (size_t)((has2 ? base + 16 : base) + r16) * 128 + kgrp;
    bf16x8 a0[4], a1[4];
    #pragma unroll
    for (int kt = 0; kt < 4; ++kt) {
        a0[kt] = *(const bf16x8*)(Ar0 + kt * 32);
        a1[kt] = *(const bf16x8*)(Ar1 + kt * 32);
    }
    int crow0 = base + (lane >> 4) * 4;
    int ccol = lane & 15;
    const bf16x8* Bv = (const bf16x8*)Bp;
    #pragma unroll
    for (int nt = 0; nt < 16; ++nt) {
        f32x4 acc0 = {0.f, 0.f, 0.f, 0.f};
        f32x4 acc1 = {0.f, 0.f, 0.f, 0.f};
        #pragma unroll
        for (int kt = 0; kt < 4; ++kt) {
            bf16x8 b = Bv[(nt * 4 + kt) * 64 + lane];
            acc0 = __builtin_amdgcn_mfma_f32_16x16x32_bf16(a0[kt], b, acc0, 0, 0, 0);
            acc1 = __builtin_amdgcn_mfma_f32_16x16x32_bf16(a1[kt], b, acc1, 0, 0, 0);
        }
        int col = nt * 16 + ccol;
        short* C = (col < 128) ? Cu : Cv;
        int cc = col & 127;
        #pragma unroll
        for (int j = 0; j < 4; ++j)
            C[(size_t)(crow0 + j) * 128 + cc] = f2bf(acc0[j]);
        if (has2) {
            #pragma unroll
            for (int j = 0; j < 4; ++j)
                C[(size_t)(crow0 + 16 + j) * 128 + cc] = f2bf(acc1[j]);
        }
    }
}

// ---------------- fused readout: h = silu(s@W1+b1); out[g] += dot(h, w2) + b2 ----------------
__global__ __launch_bounds__(256) void k_bluefused(const float* __restrict__ s,
                                                   const short* __restrict__ Bp,
                                                   const float* __restrict__ b1,
                                                   const float* __restrict__ w2,
                                                   const float* __restrict__ b2,
                                                   const int* __restrict__ graph_idx,
                                                   float* __restrict__ out, int M) {
    int lane = threadIdx.x & 63, wv = threadIdx.x >> 6;
    int tile = blockIdx.x * 4 + wv;
    int base = tile * 32;
    if (base >= M) return;
    bool has2 = (base + 16 < M);
    int r16 = lane & 15;
    int kgrp = (lane >> 4) * 8;
    int arow0 = base + r16;
    int arow1 = has2 ? (base + 16 + r16) : arow0;
    bf16x8 a0[4], a1[4];
    {
        const float* A = s + (size_t)arow0 * 128 + kgrp;
        #pragma unroll
        for (int kt = 0; kt < 4; ++kt)
            #pragma unroll
            for (int j = 0; j < 8; ++j) a0[kt][j] = f2bf(A[kt * 32 + j]);
        const float* B = s + (size_t)arow1 * 128 + kgrp;
        #pragma unroll
        for (int kt = 0; kt < 4; ++kt)
            #pragma unroll
            for (int j = 0; j < 8; ++j) a1[kt][j] = f2bf(B[kt * 32 + j]);
    }
    int crow0 = base + (lane >> 4) * 4;
    int ccol = lane & 15;
    const bf16x8* Bv = (const bf16x8*)Bp;
    float dot0[4] = {0.f, 0.f, 0.f, 0.f};
    float dot1[4] = {0.f, 0.f, 0.f, 0.f};
    #pragma unroll
    for (int nt = 0; nt < 8; ++nt) {
        f32x4 acc0 = {0.f, 0.f, 0.f, 0.f};
        f32x4 acc1 = {0.f, 0.f, 0.f, 0.f};
        #pragma unroll
        for (int kt = 0; kt < 4; ++kt) {
            bf16x8 b = Bv[(nt * 4 + kt) * 64 + lane];
            acc0 = __builtin_amdgcn_mfma_f32_16x16x32_bf16(a0[kt], b, acc0, 0, 0, 0);
            acc1 = __builtin_amdgcn_mfma_f32_16x16x32_bf16(a1[kt], b, acc1, 0, 0, 0);
        }
        int col = nt * 16 + ccol;
        float bs = b1[col], w = w2[col];
        #pragma unroll
        for (int j = 0; j < 4; ++j) {
            dot0[j] += silu_f(acc0[j] + bs) * w;
            dot1[j] += silu_f(acc1[j] + bs) * w;
        }
    }
    #pragma unroll
    for (int m = 1; m <= 8; m <<= 1) {
        #pragma unroll
        for (int j = 0; j < 4; ++j) {
            dot0[j] += __shfl_xor(dot0[j], m, 64);
            dot1[j] += __shfl_xor(dot1[j], m, 64);
        }
    }
    if (ccol == 0) {
        #pragma unroll
        for (int j = 0; j < 4; ++j) {
            int n = crow0 + j;
            atomicAdd(&out[graph_idx[n]], dot0[j] + b2[0]);
        }
        if (has2) {
            #pragma unroll
            for (int j = 0; j < 4; ++j) {
                int n = crow0 + 16 + j;
                atomicAdd(&out[graph_idx[n]], dot1[j] + b2[0]);
            }
        }
    }
}

// ---------------- embed (float4 vectorized: 4 ch/thread) ----------------
__global__ void k_embed(const int* __restrict__ z, const float* __restrict__ emb,
                        float* __restrict__ s) {
    int i = blockIdx.x * blockDim.x + threadIdx.x;   // over N_NODES*32
    if (i < N_NODES * 32) {
        int n = i >> 5, c4 = (i & 31) * 4;
        ((float4*)s)[i] = *(const float4*)&emb[(size_t)z[n] * D + c4];
    }
}

// ---------------- edge-sort precompute ----------------
__global__ void k_hist(const int* __restrict__ edges, int* __restrict__ cnt) {
    int e = blockIdx.x * 256 + threadIdx.x;
    if (e < N_EDGES) atomicAdd(&cnt[edges[2 * e]], 1);
}

// single-dispatch scan: cnt -> rowptr (exclusive), reset cnt for cursor use
#define SCH 49   // ceil(50000/1024)
__global__ __launch_bounds__(1024) void k_scanall(int* __restrict__ cnt,
                                                  int* __restrict__ rowptr) {
    __shared__ int part[1024];
    int t = threadIdx.x;
    int lo = t * SCH;
    int hi = lo + SCH; if (hi > N_NODES) hi = N_NODES;
    int sum = 0;
    for (int i = lo; i < hi; ++i) sum += cnt[i];
    part[t] = sum;
    __syncthreads();
    for (int off = 1; off < 1024; off <<= 1) {
        int v = (t >= off) ? part[t - off] : 0;
        __syncthreads();
        part[t] += v;
        __syncthreads();
    }
    int run = part[t] - sum;   // exclusive prefix
    for (int i = lo; i < hi; ++i) {
        rowptr[i] = run;
        run += cnt[i];
        cnt[i] = 0;            // reset for cursor phase
    }
    if (t == 1023) rowptr[N_NODES] = N_EDGES;
}

// scatter edges into dst-sorted order; per edge: erbf[32] bf16 (rbf*fc, fc, 0...), rhat float4
__global__ void k_scatter(const int* __restrict__ edges, const float* __restrict__ r_ij,
                          const float* __restrict__ rhat, const int* __restrict__ rowptr,
                          int* __restrict__ cursor, int* __restrict__ esrc,
                          short* __restrict__ erbf, float4* __restrict__ erhat) {
    int e = blockIdx.x * 256 + threadIdx.x;
    if (e >= N_EDGES) return;
    int dst = edges[2 * e], src = edges[2 * e + 1];
    int p = rowptr[dst] + atomicAdd(&cursor[dst], 1);
    esrc[p] = src;
    float r = r_ij[e];
    float fc = (r <= R_CUT) ? 0.5f * (cosf(PI_F * r / R_CUT) + 1.0f) : 0.0f;
    float inv_r = 1.0f / r;
    short rec[32];
    #pragma unroll
    for (int k = 0; k < N_RBF; ++k)
        rec[k] = f2bf(sinf((float)(k + 1) * (PI_F / R_CUT) * r) * inv_r * fc);
    rec[20] = f2bf(fc);
    #pragma unroll
    for (int k = 21; k < 32; ++k) rec[k] = 0;
    short* out = erbf + (size_t)p * 32;
    #pragma unroll
    for (int k = 0; k < 32; ++k) out[k] = rec[k];
    float4 rh;
    rh.x = rhat[3 * e]; rh.y = rhat[3 * e + 1]; rh.z = rhat[3 * e + 2]; rh.w = 0.f;
    erhat[p] = rh;
}

// ---------------- edge kernel v5: swapped-operand MFMA gates (b64 LDS writes) ----------------
template<bool HASV>
__global__ __launch_bounds__(128, 4) void k_edge5(
    const int* __restrict__ rowptr, const int* __restrict__ esrc,
    const short* __restrict__ erbf, const float4* __restrict__ erhat,
    const short* __restrict__ pRbf,
    const short* __restrict__ spass, const short* __restrict__ vold,
    float* __restrict__ s, short* __restrict__ vnew) {
    __shared__ __align__(16) short gate_lds[GEB * GLDS_STRIDE];
    __shared__ int   src_lds[GEB];
    __shared__ float4 rh_lds[GEB];
    __shared__ float red[64 * 9];
    int tid = threadIdx.x;
    int lane = tid & 63;
    int wv = tid >> 6;
    int ntb = wv * 12;
    int c0 = lane * 2;
    bf16x8 bfr[12];
    #pragma unroll
    for (int t = 0; t < 12; ++t)
        bfr[t] = *(const bf16x8*)(pRbf + ((size_t)((ntb + t) * 64 + lane)) * 8);
    int e16 = lane & 15;        // edge row within batch (as MFMA col after swap)
    int chb = (lane >> 4) * 4;  // channel base within tile (as MFMA row after swap)
    for (int n = blockIdx.x; n < N_NODES; n += gridDim.x) {
        int p0 = rowptr[n], p1 = rowptr[n + 1];
        float sa0 = 0.f, sa1 = 0.f;
        float va00 = 0.f, va01 = 0.f, va10 = 0.f, va11 = 0.f, va20 = 0.f, va21 = 0.f;
        for (int pb = p0; pb < p1; pb += GEB) {
            int erow = pb + e16;
            if (erow >= p1) erow = p1 - 1;
            bf16x8 afrag = *(const bf16x8*)(erbf + (size_t)erow * 32 + (lane >> 4) * 8);
            if (tid < GEB) {
                int p = pb + tid;
                if (p < p1) { src_lds[tid] = esrc[p]; rh_lds[tid] = erhat[p]; }
            }
            #pragma unroll
            for (int t = 0; t < 12; ++t) {
                f32x4 acc = {0.f, 0.f, 0.f, 0.f};
                // swapped operands: D[ch][edge]
                acc = __builtin_amdgcn_mfma_f32_16x16x32_bf16(bfr[t], afrag, acc, 0, 0, 0);
                int ct = (ntb + t) * 16 + chb;
                short4v w;
                #pragma unroll
                for (int j = 0; j < 4; ++j) w[j] = f2bf(acc[j]);
                *(short4v*)&gate_lds[e16 * GLDS_STRIDE + ct] = w;
            }
            __syncthreads();
            int pe = (pb + GEB < p1) ? pb + GEB : p1;
            for (int p = pb + wv; p < pe; p += 2) {
                int src = src_lds[p - pb];
                float4 rh = rh_lds[p - pb];
                const short* g = gate_lds + (p - pb) * GLDS_STRIDE;
                unsigned ga1 = *(const unsigned*)(g + 128 + c0);
                unsigned ga2 = *(const unsigned*)(g + 256 + c0);
                const short* sp = spass + (size_t)src * D3;
                unsigned sp1 = *(const unsigned*)(sp + 128 + c0);
                unsigned sp2 = *(const unsigned*)(sp + 256 + c0);
                sa0 += bflo(ga1) * bflo(sp1);
                sa1 += bfhi(ga1) * bfhi(sp1);
                float drl = bflo(ga2) * bflo(sp2);
                float drh = bfhi(ga2) * bfhi(sp2);
                if (HASV) {
                    unsigned ga0 = *(const unsigned*)(g + c0);
                    unsigned sp0 = *(const unsigned*)(sp + c0);
                    float dvl = bflo(ga0) * bflo(sp0);
                    float dvh = bfhi(ga0) * bfhi(sp0);
                    const short* vs = vold + (size_t)src * D3;
                    unsigned v0 = *(const unsigned*)(vs + c0);
                    unsigned v1 = *(const unsigned*)(vs + 128 + c0);
                    unsigned v2 = *(const unsigned*)(vs + 256 + c0);
                    va00 += bflo(v0) * dvl + rh.x * drl;
                    va01 += bfhi(v0) * dvh + rh.x * drh;
                    va10 += bflo(v1) * dvl + rh.y * drl;
                    va11 += bfhi(v1) * dvh + rh.y * drh;
                    va20 += bflo(v2) * dvl + rh.z * drl;
                    va21 += bfhi(v2) * dvh + rh.z * drh;
                } else {
                    va00 += rh.x * drl; va01 += rh.x * drh;
                    va10 += rh.y * drl; va11 += rh.y * drh;
                    va20 += rh.z * drl; va21 += rh.z * drh;
                }
            }
            __syncthreads();
        }
        float* rl = red + lane * 9;
        __syncthreads();
        if (wv == 1) {
            rl[0] = sa0; rl[1] = sa1;
            rl[2] = va00; rl[3] = va01; rl[4] = va10; rl[5] = va11; rl[6] = va20; rl[7] = va21;
        }
        __syncthreads();
        if (wv == 0) {
            sa0 += rl[0]; sa1 += rl[1];
            va00 += rl[2]; va01 += rl[3]; va10 += rl[4]; va11 += rl[5]; va20 += rl[6]; va21 += rl[7];
            float2 sv = *(float2*)(s + (size_t)n * D + c0);
            sv.x += sa0; sv.y += sa1;
            *(float2*)(s + (size_t)n * D + c0) = sv;
            size_t vb = (size_t)n * D3;
            if (HASV) {
                unsigned o0 = *(const unsigned*)(vold + vb + c0);
                unsigned o1 = *(const unsigned*)(vold + vb + 128 + c0);
                unsigned o2 = *(const unsigned*)(vold + vb + 256 + c0);
                va00 += bflo(o0); va01 += bfhi(o0);
                va10 += bflo(o1); va11 += bfhi(o1);
                va20 += bflo(o2); va21 += bfhi(o2);
            }
            *(unsigned*)(vnew + vb + c0)       = packbf(va00, va01);
            *(unsigned*)(vnew + vb + 128 + c0) = packbf(va10, va11);
            *(unsigned*)(vnew + vb + 256 + c0) = packbf(va20, va21);
        }
    }
}

// ---------------- V_norm, 2 channels/thread (uint loads) ----------------
__global__ void k_svbuild(const short* __restrict__ Vv, short* __restrict__ Vn) {
    int i = blockIdx.x * 256 + threadIdx.x;   // over N_NODES*64
    int n = i >> 6, c0 = (i & 63) * 2;
    size_t vb = (size_t)n * D3;
    unsigned v0 = *(const unsigned*)(Vv + vb + c0);
    unsigned v1 = *(const unsigned*)(Vv + vb + 128 + c0);
    unsigned v2 = *(const unsigned*)(Vv + vb + 256 + c0);
    float a = bflo(v0), b = bflo(v1), c = bflo(v2);
    float d = bfhi(v0), e = bfhi(v1), f = bfhi(v2);
    *(unsigned*)(Vn + (size_t)n * D + c0) =
        packbf(sqrtf(a * a + b * b + c * c), sqrtf(d * d + e * e + f * f));
}

// ---------------- apply gated update, 2 channels/thread ----------------
__global__ void k_apply(float* __restrict__ s, short* __restrict__ v,
                        const short* __restrict__ Uv, const short* __restrict__ Vv,
                        const short* __restrict__ a_bf) {
    int i = blockIdx.x * 256 + threadIdx.x;   // over N_NODES*64
    int n = i >> 6, c0 = (i & 63) * 2;
    size_t ab = (size_t)n * D3;
    unsigned avv = *(const unsigned*)(a_bf + ab + c0);
    unsigned asv = *(const unsigned*)(a_bf + ab + 128 + c0);
    unsigned ass = *(const unsigned*)(a_bf + ab + 256 + c0);
    float scal0 = 0.f, scal1 = 0.f;
    float u0[3], u1[3];
    #pragma unroll
    for (int d = 0; d < 3; ++d) {
        unsigned uu = *(const unsigned*)(Uv + ab + d * 128 + c0);
        unsigned vv = *(const unsigned*)(Vv + ab + d * 128 + c0);
        u0[d] = bflo(uu); u1[d] = bfhi(uu);
        scal0 += u0[d] * bflo(vv);
        scal1 += u1[d] * bfhi(vv);
    }
    float2 sv = *(float2*)(s + (size_t)n * D + c0);
    sv.x += scal0 * bflo(asv) + bflo(ass);
    sv.y += scal1 * bfhi(asv) + bfhi(ass);
    *(float2*)(s + (size_t)n * D + c0) = sv;
    float a0 = bflo(avv), a1 = bfhi(avv);
    #pragma unroll
    for (int d = 0; d < 3; ++d) {
        unsigned* vp = (unsigned*)(v + ab + d * 128 + c0);
        unsigned old = *vp;
        *vp = packbf(bflo(old) + a0 * u0[d], bfhi(old) + a1 * u1[d]);
    }
}

static inline int g32(int M) { int t = (M + 31) / 32; return (t + 3) / 4; }

extern "C" void kernel_launch(void* const* d_in, const int* in_sizes, int n_in,
                              void* d_out, int out_size, void* d_ws, size_t ws_size,
                              hipStream_t stream) {
    const int*   z         = (const int*)d_in[0];
    const int*   edges     = (const int*)d_in[1];
    const float* r_ij      = (const float*)d_in[2];
    const float* rhat      = (const float*)d_in[3];
    const int*   graph_idx = (const int*)d_in[4];
    const float* emb       = (const float*)d_in[5];
    const float* msg_w1    = (const float*)d_in[6];
    const float* msg_b1    = (const float*)d_in[7];
    const float* msg_w2    = (const float*)d_in[8];
    const float* msg_b2    = (const float*)d_in[9];
    const float* rbf_w     = (const float*)d_in[10];
    const float* rbf_b     = (const float*)d_in[11];
    const float* upd_U     = (const float*)d_in[12];
    const float* upd_V     = (const float*)d_in[13];
    const float* upd_w1    = (const float*)d_in[14];
    const float* upd_b1    = (const float*)d_in[15];
    const float* upd_w2    = (const float*)d_in[16];
    const float* upd_b2    = (const float*)d_in[17];
    const float* blue_w1   = (const float*)d_in[18];
    const float* blue_b1   = (const float*)d_in[19];
    const float* blue_w2   = (const float*)d_in[20];
    const float* blue_b2   = (const float*)d_in[21];
    float* out = (float*)d_out;

    char* ws = (char*)d_ws;
    size_t off = 0;
    auto alloc = [&](size_t bytes) { void* p = ws + off; off += (bytes + 255) & ~(size_t)255; return p; };

    float* s      = (float*)alloc((size_t)N_NODES * D * 4);            // 25.6 MB
    short* bufV0  = (short*)alloc((size_t)N_NODES * D3 * 2);           // 38.4 MB
    short* bufV1  = (short*)alloc((size_t)N_NODES * D3 * 2);           // 38.4 MB
    short* shrd   = (short*)alloc((size_t)N_NODES * D3 * 2);           // 38.4 MB: s_pass -> a
    short* VnBuf  = (short*)alloc((size_t)N_NODES * D * 2);            // 12.8 MB (V_norm)
    short* Vv     = (short*)alloc((size_t)N_NODES * D3 * 2);           // 38.4 MB
    // edge tables
    int*    esrc   = (int*)alloc((size_t)N_EDGES * 4);                 // 1.6 MB
    short*  erbf   = (short*)alloc((size_t)N_EDGES * 32 * 2);          // 25.6 MB
    float4* erhat  = (float4*)alloc((size_t)N_EDGES * 16);             // 6.4 MB
    int*    rowptr = (int*)alloc((size_t)(N_NODES + 1) * 4);
    int*    cnt    = (int*)alloc((size_t)N_NODES * 4);                 // hist then cursor

    // packed weights
    short* pBlue = (short*)alloc(16384 * 2);
    short* pRbfAll = (short*)alloc((size_t)3 * 12288 * 2);
    short* pMsgW1[3]; short* pMsgW2[3]; short* pUV[3]; short* pUpdW1[3]; short* pUpdW2[3];
    for (int i = 0; i < 3; ++i) {
        pMsgW1[i] = (short*)alloc(16384 * 2);
        pMsgW2[i] = (short*)alloc(49152 * 2);
        pUV[i]    = (short*)alloc(32768 * 2);   // U tiles then V tiles
        pUpdW1[i] = (short*)alloc(32768 * 2);
        pUpdW2[i] = (short*)alloc(49152 * 2);
    }

    // ---- all GEMM-weight packs in one dispatch ----
    PackJobs jobs;
    jobs.njobs = 0;
    int bacc = 0;
    auto addjob = [&](const float* W, short* P, int K, int N) {
        int j = jobs.njobs++;
        jobs.W[j] = W; jobs.P[j] = P; jobs.K[j] = K; jobs.N[j] = N;
        jobs.boff[j] = bacc;
        int total = (N / 16) * (K / 32) * 64;
        bacc += (total + 255) / 256;
        jobs.boff[j + 1] = bacc;
    };
    addjob(blue_w1, pBlue, 128, 128);
    for (int i = 0; i < 3; ++i) {
        addjob(msg_w1 + (size_t)i * D * D,     pMsgW1[i], 128, 128);
        addjob(msg_w2 + (size_t)i * D * D3,    pMsgW2[i], 128, 384);
        addjob(upd_U  + (size_t)i * D * D,     pUV[i],          128, 128);
        addjob(upd_V  + (size_t)i * D * D,     pUV[i] + 16384,  128, 128);
        addjob(upd_w1 + (size_t)i * 2 * D * D, pUpdW1[i], 256, 128);
        addjob(upd_w2 + (size_t)i * D * D3,    pUpdW2[i], 128, 384);
    }
    k_packall<<<bacc, 256, 0, stream>>>(jobs);
    k_packrbf<<<18, 256, 0, stream>>>(rbf_w, rbf_b, pRbfAll);

    // ---- edge sort precompute (once per launch) ----
    hipMemsetAsync(cnt, 0, (size_t)N_NODES * 4, stream);
    k_hist<<<(N_EDGES + 255) / 256, 256, 0, stream>>>(edges, cnt);
    k_scanall<<<1, 1024, 0, stream>>>(cnt, rowptr);   // also resets cnt for cursor
    k_scatter<<<(N_EDGES + 255) / 256, 256, 0, stream>>>(edges, r_ij, rhat, rowptr, cnt,
                                                         esrc, erbf, erhat);

    // ---- state init ----
    hipMemsetAsync(d_out, 0, (size_t)out_size * sizeof(float), stream);
    k_embed<<<(N_NODES * 32 + 255) / 256, 256, 0, stream>>>(z, emb, s);

    const int gN  = g32(N_NODES);
    const int gN3 = g32(N_NODES * 3);

    for (int i = 0; i < 3; ++i) {
        short* vstate = (i & 1) ? bufV1 : bufV0;   // current v (bf16)
        short* vscr   = (i & 1) ? bufV0 : bufV1;   // next v
        // s_pass = silu(s @ msg_w1 + b1) @ msg_w2 + b2   [fused 2-layer MLP]
        k_mlp2<128, 1><<<gN, 256, 0, stream>>>(
            s, nullptr, pMsgW1[i], msg_b1 + (size_t)i * D,
            pMsgW2[i], msg_b2 + (size_t)i * D3, shrd, N_NODES);
        // segment-sum edge gather with MFMA gates: s += ds ; vscr = vstate + dv
        if (i == 0)
            k_edge5<false><<<4096, 128, 0, stream>>>(rowptr, esrc, erbf, erhat,
                                                     pRbfAll, shrd, vstate, s, vscr);
        else
            k_edge5<true><<<4096, 128, 0, stream>>>(rowptr, esrc, erbf, erhat,
                                                    pRbfAll + (size_t)i * 12288,
                                                    shrd, vstate, s, vscr);
        // Uv (into dead vstate buffer) and Vv in ONE GEMM (single A read)
        k_gemmUV<<<gN3, 256, 0, stream>>>(vscr, pUV[i], vstate, Vv, N_NODES * 3);
        // V_norm -> VnBuf (vectorized)
        k_svbuild<<<(N_NODES * 64) / 256, 256, 0, stream>>>(Vv, VnBuf);
        // a = silu([Vn | s] @ upd_w1 + b1) @ upd_w2 + b2   [fused 2-layer MLP]
        k_mlp2<256, 2><<<gN, 256, 0, stream>>>(
            VnBuf, s, pUpdW1[i], upd_b1 + (size_t)i * D,
            pUpdW2[i], upd_b2 + (size_t)i * D3, shrd, N_NODES);
        // gated update of s and v (in place on vscr), 2 ch/thread
        k_apply<<<(N_NODES * 64) / 256, 256, 0, stream>>>(s, vscr, vstate, Vv, shrd);
    }

    // fused readout
    k_bluefused<<<gN, 256, 0, stream>>>(s, pBlue, blue_b1, blue_w2, blue_b2,
                                        graph_idx, out, N_NODES);
}